// Round 3
// baseline (3020.430 us; speedup 1.0000x reference)
//
#include <hip/hip_runtime.h>
#include <math.h>

// ---------------- GEMM: C[rows][128] = relu(concat(A1,A2)[rows][Ktot] @ W[Ktot][128] + bias) ----------------
#define BM 64
#define KC 32

__global__ __launch_bounds__(256) void gemm_relu_kernel(
    const float* __restrict__ A1, const float* __restrict__ A2,
    int K1, int Ktot,
    const float* __restrict__ W, const float* __restrict__ bias,
    float* __restrict__ C, int rows)
{
    __shared__ float At[KC][BM + 4];   // A chunk, transposed: At[k][row]
    __shared__ float Ws[KC][128];      // W chunk
    const int tid  = threadIdx.x;
    const int row0 = blockIdx.x * BM;
    const int trow = tid >> 4;   // 0..15 -> rows trow*4 .. trow*4+3
    const int tcol = tid & 15;   // 0..15 -> cols tcol*4..+3 and 64+tcol*4..+3

    float acc[4][8];
#pragma unroll
    for (int r = 0; r < 4; ++r)
#pragma unroll
        for (int c = 0; c < 8; ++c) acc[r][c] = 0.f;

    for (int k0 = 0; k0 < Ktot; k0 += KC) {
        const float* A; int ka, lda;
        if (k0 < K1) { A = A1; ka = k0;      lda = K1; }
        else         { A = A2; ka = k0 - K1; lda = Ktot - K1; }

        // stage A chunk transposed: 64 rows x 32 k
        {
            const int kk = tid & 31;
            const int i0 = tid >> 5;  // 0..7
#pragma unroll
            for (int p = 0; p < 8; ++p) {
                const int i  = i0 + p * 8;
                const int gr = row0 + i;
                At[kk][i] = (gr < rows) ? A[(long long)gr * lda + ka + kk] : 0.f;
            }
        }
        // stage W chunk: 32 x 128 (float4)
        {
#pragma unroll
            for (int p = 0; p < 4; ++p) {
                const int f4 = tid + p * 256;          // 0..1023
                const int r  = f4 >> 5, c4 = f4 & 31;
                *(float4*)&Ws[r][c4 * 4] =
                    *(const float4*)&W[(long long)(k0 + r) * 128 + c4 * 4];
            }
        }
        __syncthreads();

#pragma unroll 8
        for (int kk = 0; kk < KC; ++kk) {
            const float4 a  = *(const float4*)&At[kk][trow * 4];
            const float4 w0 = *(const float4*)&Ws[kk][tcol * 4];
            const float4 w1 = *(const float4*)&Ws[kk][64 + tcol * 4];
            const float av[4] = {a.x, a.y, a.z, a.w};
            const float wv[8] = {w0.x, w0.y, w0.z, w0.w, w1.x, w1.y, w1.z, w1.w};
#pragma unroll
            for (int r = 0; r < 4; ++r)
#pragma unroll
                for (int c = 0; c < 8; ++c) acc[r][c] += av[r] * wv[c];
        }
        __syncthreads();
    }

    // epilogue: bias + relu + store
#pragma unroll
    for (int r = 0; r < 4; ++r) {
        const int gr = row0 + trow * 4 + r;
        if (gr >= rows) continue;
        float4 o0, o1;
        o0.x = fmaxf(acc[r][0] + bias[tcol * 4 + 0], 0.f);
        o0.y = fmaxf(acc[r][1] + bias[tcol * 4 + 1], 0.f);
        o0.z = fmaxf(acc[r][2] + bias[tcol * 4 + 2], 0.f);
        o0.w = fmaxf(acc[r][3] + bias[tcol * 4 + 3], 0.f);
        o1.x = fmaxf(acc[r][4] + bias[64 + tcol * 4 + 0], 0.f);
        o1.y = fmaxf(acc[r][5] + bias[64 + tcol * 4 + 1], 0.f);
        o1.z = fmaxf(acc[r][6] + bias[64 + tcol * 4 + 2], 0.f);
        o1.w = fmaxf(acc[r][7] + bias[64 + tcol * 4 + 3], 0.f);
        *(float4*)&C[(long long)gr * 128 + tcol * 4]      = o0;
        *(float4*)&C[(long long)gr * 128 + 64 + tcol * 4] = o1;
    }
}

// ---------------- edge scatter: agg[dst] += messages[src], 128 feats per edge ----------------
__global__ __launch_bounds__(256) void edge_scatter_kernel(
    const int* __restrict__ src, const int* __restrict__ dst,
    const float* __restrict__ msg, float* __restrict__ agg, long long total)
{
    const long long idx = (long long)blockIdx.x * 256 + threadIdx.x;
    if (idx >= total) return;
    const int e  = (int)(idx >> 5);
    const int c4 = (int)(idx & 31);
    const int s = src[e], d = dst[e];
    const float4 m = ((const float4*)msg)[(long long)s * 32 + c4];
    float* b = agg + (long long)d * 128 + c4 * 4;
    atomicAdd(b + 0, m.x);
    atomicAdd(b + 1, m.y);
    atomicAdd(b + 2, m.z);
    atomicAdd(b + 3, m.w);
}

// ---------------- actor/critic heads: logits[N], crit[N] ----------------
__global__ __launch_bounds__(256) void head_kernel(
    const float* __restrict__ U,
    const float* __restrict__ Wa1, const float* __restrict__ ba1,
    const float* __restrict__ Wa2, const float* __restrict__ ba2,
    const float* __restrict__ Wc1, const float* __restrict__ bc1,
    const float* __restrict__ Wc2, const float* __restrict__ bc2,
    float* __restrict__ logits, float* __restrict__ crit)
{
    __shared__ float Wht[32][132];   // transposed: Wht[col][k], cols 0-15 actor, 16-31 critic
    __shared__ float u_lds[8][132];
    __shared__ float w2[32], hb[32];
    const int tid = threadIdx.x;

    for (int idx = tid; idx < 4096; idx += 256) {
        const int k = idx & 127, col = idx >> 7;
        Wht[col][k] = (col < 16) ? Wa1[k * 16 + col] : Wc1[k * 16 + (col - 16)];
    }
    if (tid < 32) {
        w2[tid] = (tid < 16) ? Wa2[tid] : Wc2[tid - 16];
        hb[tid] = (tid < 16) ? ba1[tid] : bc1[tid - 16];
    }
    const int node0 = blockIdx.x * 8;
    {
        const int row = tid >> 5, c4 = tid & 31;
        *(float4*)&u_lds[row][c4 * 4] =
            *(const float4*)&U[(long long)(node0 + row) * 128 + c4 * 4];
    }
    __syncthreads();

    const int nl  = tid >> 5;   // node within block
    const int col = tid & 31;   // head column
    float acc = hb[col];
    const float4* up = (const float4*)&u_lds[nl][0];
    const float4* wp = (const float4*)&Wht[col][0];
#pragma unroll 8
    for (int k4 = 0; k4 < 32; ++k4) {
        const float4 u = up[k4], w = wp[k4];
        acc += u.x * w.x; acc += u.y * w.y; acc += u.z * w.z; acc += u.w * w.w;
    }
    float val = fmaxf(acc, 0.f) * w2[col];
#pragma unroll
    for (int off = 8; off >= 1; off >>= 1) val += __shfl_xor(val, off);
    const int node = node0 + nl;
    if (col == 0)  logits[node] = val + ba2[0];
    if (col == 16) crit[node]   = val + bc2[0];
}

// ---------------- per-graph finalize: log_prob, entropy, value, actions ----------------
__device__ __forceinline__ float blockRedMax(float v, float* red) {
#pragma unroll
    for (int o = 32; o >= 1; o >>= 1) v = fmaxf(v, __shfl_xor(v, o));
    const int w = threadIdx.x >> 6;
    __syncthreads();
    if ((threadIdx.x & 63) == 0) red[w] = v;
    __syncthreads();
    if (threadIdx.x < 16) {
        float x = red[threadIdx.x];
#pragma unroll
        for (int o = 8; o >= 1; o >>= 1) x = fmaxf(x, __shfl_xor(x, o));
        if (threadIdx.x == 0) red[0] = x;
    }
    __syncthreads();
    const float r = red[0];
    __syncthreads();
    return r;
}

__device__ __forceinline__ float blockRedSum(float v, float* red) {
#pragma unroll
    for (int o = 32; o >= 1; o >>= 1) v += __shfl_xor(v, o);
    const int w = threadIdx.x >> 6;
    __syncthreads();
    if ((threadIdx.x & 63) == 0) red[w] = v;
    __syncthreads();
    if (threadIdx.x < 16) {
        float x = red[threadIdx.x];
#pragma unroll
        for (int o = 8; o >= 1; o >>= 1) x += __shfl_xor(x, o);
        if (threadIdx.x == 0) red[0] = x;
    }
    __syncthreads();
    const float r = red[0];
    __syncthreads();
    return r;
}

__global__ __launch_bounds__(1024) void finalize_kernel(
    const float* __restrict__ logits, const float* __restrict__ crit,
    const int* __restrict__ actions, float* __restrict__ out, int NP, int G)
{
    __shared__ float slog[12512];   // NP <= 12512
    __shared__ float red[16];
    const int g = blockIdx.x;
    const int tid = threadIdx.x;
    const float* lg = logits + (long long)g * NP;
    const float* cg = crit   + (long long)g * NP;

    float lmax = -3.402823466e38f, cmax = -3.402823466e38f, csum = 0.f;
    for (int i = tid; i < NP; i += 1024) {
        const float l = lg[i], c = cg[i];
        slog[i] = l;
        lmax = fmaxf(lmax, l);
        cmax = fmaxf(cmax, c);
        csum += c;
    }
    __syncthreads();
    lmax = blockRedMax(lmax, red);
    cmax = blockRedMax(cmax, red);
    csum = blockRedSum(csum, red);

    float zsum = 0.f, ssum = 0.f;
    for (int i = tid; i < NP; i += 1024) {
        const float s = slog[i];
        const float e = expf(s - lmax);
        zsum += e;
        ssum += s * e;
    }
    zsum = blockRedSum(zsum, red);
    ssum = blockRedSum(ssum, red);

    if (tid == 0) {
        const int a = actions[g];
        const float sa   = slog[a];
        const float logZ = logf(zsum) + lmax;
        const float lp   = sa - logZ;
        const float H    = logZ - ssum / zsum;
        const float v    = cmax * 0.5f + (csum / (float)NP) * 0.5f;
        out[g]         = (float)a;   // actions echoed as float
        out[G + g]     = lp;
        out[2 * G + g] = H;
        out[3 * G + g] = v;
    }
}

extern "C" void kernel_launch(void* const* d_in, const int* in_sizes, int n_in,
                              void* d_out, int out_size, void* d_ws, size_t ws_size,
                              hipStream_t stream)
{
    const float* inputs = (const float*)d_in[0];
    const float* W_in   = (const float*)d_in[1];
    const float* b_in   = (const float*)d_in[2];
    const float* W_msg  = (const float*)d_in[3];
    const float* b_msg  = (const float*)d_in[4];
    const float* W_upd  = (const float*)d_in[5];
    const float* b_upd  = (const float*)d_in[6];
    const float* W_a1   = (const float*)d_in[7];
    const float* b_a1   = (const float*)d_in[8];
    const float* W_a2   = (const float*)d_in[9];
    const float* b_a2   = (const float*)d_in[10];
    const float* W_c1   = (const float*)d_in[11];
    const float* b_c1   = (const float*)d_in[12];
    const float* W_c2   = (const float*)d_in[13];
    const float* b_c2   = (const float*)d_in[14];
    const int* edge_src = (const int*)d_in[15];
    const int* edge_dst = (const int*)d_in[16];
    const int* actions  = (const int*)d_in[17];

    const int N  = in_sizes[0] / 128;
    const int E  = in_sizes[15];
    const int G  = in_sizes[17];
    const int NP = N / G;

    float* out         = (float*)d_out;
    float* node_states = out;                       // reuse updates region [N*128]
    float* msg    = (float*)d_ws;                   // [N*128]
    float* agg    = msg + (size_t)N * 128;          // [N*128]
    float* logits = agg + (size_t)N * 128;          // [N]
    float* crit   = logits + N;                     // [N]

    hipMemsetAsync(agg, 0, (size_t)N * 128 * sizeof(float), stream);

    const int gemmGrid = (N + BM - 1) / BM;
    // node_states = relu(inputs @ W_in + b_in)  -> d_out region
    gemm_relu_kernel<<<gemmGrid, 256, 0, stream>>>(inputs, nullptr, 128, 128, W_in, b_in, node_states, N);
    // messages = relu(node_states @ W_msg + b_msg)
    gemm_relu_kernel<<<gemmGrid, 256, 0, stream>>>(node_states, nullptr, 128, 128, W_msg, b_msg, msg, N);
    // agg = segment_sum(messages[src] by dst)
    const long long total = (long long)E * 32;
    const int egrid = (int)((total + 255) / 256);
    edge_scatter_kernel<<<egrid, 256, 0, stream>>>(edge_src, edge_dst, msg, agg, total);
    // updates = relu([agg | node_states] @ W_upd + b_upd)  -> in-place over node_states in d_out
    gemm_relu_kernel<<<gemmGrid, 256, 0, stream>>>(agg, node_states, 128, 256, W_upd, b_upd, out, N);
    // heads
    head_kernel<<<N / 8, 256, 0, stream>>>(out, W_a1, b_a1, W_a2, b_a2, W_c1, b_c1, W_c2, b_c2, logits, crit);
    // per-graph outputs
    finalize_kernel<<<G, 1024, 0, stream>>>(logits, crit, actions, out + (size_t)N * 128, NP, G);
}

// Round 4
// 630.116 us; speedup vs baseline: 4.7935x; 4.7935x over previous
//
#include <hip/hip_runtime.h>
#include <math.h>

// ---------------- GEMM: C[rows][128] = relu(concat(A1,A2)[rows][Ktot] @ W[Ktot][128] + bias) ----------------
#define BM 64
#define KC 32

__global__ __launch_bounds__(256) void gemm_relu_kernel(
    const float* __restrict__ A1, const float* __restrict__ A2,
    int K1, int Ktot,
    const float* __restrict__ W, const float* __restrict__ bias,
    float* __restrict__ C, int rows)
{
    __shared__ float At[KC][BM + 4];   // A chunk, transposed: At[k][row]
    __shared__ float Ws[KC][128];      // W chunk
    const int tid  = threadIdx.x;
    const int row0 = blockIdx.x * BM;
    const int trow = tid >> 4;   // 0..15 -> rows trow*4 .. trow*4+3
    const int tcol = tid & 15;   // 0..15 -> cols tcol*4..+3 and 64+tcol*4..+3

    float acc[4][8];
#pragma unroll
    for (int r = 0; r < 4; ++r)
#pragma unroll
        for (int c = 0; c < 8; ++c) acc[r][c] = 0.f;

    for (int k0 = 0; k0 < Ktot; k0 += KC) {
        const float* A; int ka, lda;
        if (k0 < K1) { A = A1; ka = k0;      lda = K1; }
        else         { A = A2; ka = k0 - K1; lda = Ktot - K1; }

        // stage A chunk transposed: 64 rows x 32 k
        {
            const int kk = tid & 31;
            const int i0 = tid >> 5;  // 0..7
#pragma unroll
            for (int p = 0; p < 8; ++p) {
                const int i  = i0 + p * 8;
                const int gr = row0 + i;
                At[kk][i] = (gr < rows) ? A[(long long)gr * lda + ka + kk] : 0.f;
            }
        }
        // stage W chunk: 32 x 128 (float4)
        {
#pragma unroll
            for (int p = 0; p < 4; ++p) {
                const int f4 = tid + p * 256;          // 0..1023
                const int r  = f4 >> 5, c4 = f4 & 31;
                *(float4*)&Ws[r][c4 * 4] =
                    *(const float4*)&W[(long long)(k0 + r) * 128 + c4 * 4];
            }
        }
        __syncthreads();

#pragma unroll 8
        for (int kk = 0; kk < KC; ++kk) {
            const float4 a  = *(const float4*)&At[kk][trow * 4];
            const float4 w0 = *(const float4*)&Ws[kk][tcol * 4];
            const float4 w1 = *(const float4*)&Ws[kk][64 + tcol * 4];
            const float av[4] = {a.x, a.y, a.z, a.w};
            const float wv[8] = {w0.x, w0.y, w0.z, w0.w, w1.x, w1.y, w1.z, w1.w};
#pragma unroll
            for (int r = 0; r < 4; ++r)
#pragma unroll
                for (int c = 0; c < 8; ++c) acc[r][c] += av[r] * wv[c];
        }
        __syncthreads();
    }

    // epilogue: bias + relu + store
#pragma unroll
    for (int r = 0; r < 4; ++r) {
        const int gr = row0 + trow * 4 + r;
        if (gr >= rows) continue;
        float4 o0, o1;
        o0.x = fmaxf(acc[r][0] + bias[tcol * 4 + 0], 0.f);
        o0.y = fmaxf(acc[r][1] + bias[tcol * 4 + 1], 0.f);
        o0.z = fmaxf(acc[r][2] + bias[tcol * 4 + 2], 0.f);
        o0.w = fmaxf(acc[r][3] + bias[tcol * 4 + 3], 0.f);
        o1.x = fmaxf(acc[r][4] + bias[64 + tcol * 4 + 0], 0.f);
        o1.y = fmaxf(acc[r][5] + bias[64 + tcol * 4 + 1], 0.f);
        o1.z = fmaxf(acc[r][6] + bias[64 + tcol * 4 + 2], 0.f);
        o1.w = fmaxf(acc[r][7] + bias[64 + tcol * 4 + 3], 0.f);
        *(float4*)&C[(long long)gr * 128 + tcol * 4]      = o0;
        *(float4*)&C[(long long)gr * 128 + 64 + tcol * 4] = o1;
    }
}

// ---------------- CSR build ----------------
__global__ __launch_bounds__(256) void count_edges_kernel(
    const int* __restrict__ dst, int* __restrict__ counts, int E)
{
    const int i = blockIdx.x * 256 + threadIdx.x;
    if (i < E) atomicAdd(&counts[dst[i]], 1);
}

// per-block (1024-element) sums of counts
__global__ __launch_bounds__(256) void block_reduce_kernel(
    const int* __restrict__ counts, int* __restrict__ bsum, int N)
{
    const int b = blockIdx.x, t = threadIdx.x;
    const int base = b * 1024 + t * 4;
    int s = 0;
#pragma unroll
    for (int k = 0; k < 4; ++k)
        if (base + k < N) s += counts[base + k];
#pragma unroll
    for (int off = 1; off < 64; off <<= 1) s += __shfl_xor(s, off);
    __shared__ int ws[4];
    if ((t & 63) == 0) ws[t >> 6] = s;
    __syncthreads();
    if (t == 0) bsum[b] = ws[0] + ws[1] + ws[2] + ws[3];
}

// exclusive scan of block sums (NB <= 256), also writes offs[N] = E
__global__ __launch_bounds__(256) void scan_sums_kernel(
    const int* __restrict__ bsum, int* __restrict__ bpref, int NB,
    int* __restrict__ offs, int N, int E)
{
    const int t = threadIdx.x;
    const int v = (t < NB) ? bsum[t] : 0;
    const int lane = t & 63, wid = t >> 6;
    int x = v;
#pragma unroll
    for (int off = 1; off < 64; off <<= 1) {
        const int y = __shfl_up(x, off);
        if (lane >= off) x += y;
    }
    __shared__ int ws[4], wp[4];
    if (lane == 63) ws[wid] = x;
    __syncthreads();
    if (t == 0) { int s = 0; for (int w = 0; w < 4; ++w) { wp[w] = s; s += ws[w]; } }
    __syncthreads();
    if (t < NB) bpref[t] = x - v + wp[wid];
    if (t == 0) offs[N] = E;
}

// exclusive scan within each 1024-chunk + block prefix -> offs, cursor
__global__ __launch_bounds__(256) void scan_apply_kernel(
    const int* __restrict__ counts, const int* __restrict__ bpref,
    int* __restrict__ offs, int* __restrict__ cursor, int N)
{
    const int b = blockIdx.x, t = threadIdx.x;
    const int base = b * 1024 + t * 4;
    int v[4];
    int tsum = 0;
#pragma unroll
    for (int k = 0; k < 4; ++k) {
        v[k] = (base + k < N) ? counts[base + k] : 0;
        tsum += v[k];
    }
    const int lane = t & 63, wid = t >> 6;
    int x = tsum;
#pragma unroll
    for (int off = 1; off < 64; off <<= 1) {
        const int y = __shfl_up(x, off);
        if (lane >= off) x += y;
    }
    __shared__ int ws[4], wp[4];
    if (lane == 63) ws[wid] = x;
    __syncthreads();
    if (t == 0) { int s = 0; for (int w = 0; w < 4; ++w) { wp[w] = s; s += ws[w]; } }
    __syncthreads();
    int run = x - tsum + wp[wid] + bpref[b];
#pragma unroll
    for (int k = 0; k < 4; ++k) {
        if (base + k < N) {
            offs[base + k]   = run;
            cursor[base + k] = run;
            run += v[k];
        }
    }
}

__global__ __launch_bounds__(256) void fill_csr_kernel(
    const int* __restrict__ src, const int* __restrict__ dst,
    int* __restrict__ cursor, int* __restrict__ csr, int E)
{
    const int i = blockIdx.x * 256 + threadIdx.x;
    if (i < E) {
        const int p = atomicAdd(&cursor[dst[i]], 1);
        csr[p] = src[i];
    }
}

// ---------------- gather: agg[n] = sum over in-edges of msg[src] ----------------
__global__ __launch_bounds__(256) void gather_kernel(
    const int* __restrict__ offs, const int* __restrict__ csr,
    const float* __restrict__ msg, float* __restrict__ agg, int N)
{
    const int node = blockIdx.x * 8 + (threadIdx.x >> 5);
    if (node >= N) return;
    const int c4 = threadIdx.x & 31;
    const int j1 = offs[node + 1];
    int j = offs[node];
    const float4* mv = (const float4*)msg;
    float4 acc = make_float4(0.f, 0.f, 0.f, 0.f);
    for (; j + 1 < j1; j += 2) {
        const int s0 = csr[j], s1 = csr[j + 1];
        const float4 a = mv[(long long)s0 * 32 + c4];
        const float4 b = mv[(long long)s1 * 32 + c4];
        acc.x += a.x; acc.y += a.y; acc.z += a.z; acc.w += a.w;
        acc.x += b.x; acc.y += b.y; acc.z += b.z; acc.w += b.w;
    }
    if (j < j1) {
        const int s = csr[j];
        const float4 a = mv[(long long)s * 32 + c4];
        acc.x += a.x; acc.y += a.y; acc.z += a.z; acc.w += a.w;
    }
    ((float4*)agg)[(long long)node * 32 + c4] = acc;
}

// ---------------- actor/critic heads: logits[N], crit[N] ----------------
__global__ __launch_bounds__(256) void head_kernel(
    const float* __restrict__ U,
    const float* __restrict__ Wa1, const float* __restrict__ ba1,
    const float* __restrict__ Wa2, const float* __restrict__ ba2,
    const float* __restrict__ Wc1, const float* __restrict__ bc1,
    const float* __restrict__ Wc2, const float* __restrict__ bc2,
    float* __restrict__ logits, float* __restrict__ crit)
{
    __shared__ float Wht[32][132];   // transposed: Wht[col][k], cols 0-15 actor, 16-31 critic
    __shared__ float u_lds[8][132];
    __shared__ float w2[32], hb[32];
    const int tid = threadIdx.x;

    for (int idx = tid; idx < 4096; idx += 256) {
        const int k = idx & 127, col = idx >> 7;
        Wht[col][k] = (col < 16) ? Wa1[k * 16 + col] : Wc1[k * 16 + (col - 16)];
    }
    if (tid < 32) {
        w2[tid] = (tid < 16) ? Wa2[tid] : Wc2[tid - 16];
        hb[tid] = (tid < 16) ? ba1[tid] : bc1[tid - 16];
    }
    const int node0 = blockIdx.x * 8;
    {
        const int row = tid >> 5, c4 = tid & 31;
        *(float4*)&u_lds[row][c4 * 4] =
            *(const float4*)&U[(long long)(node0 + row) * 128 + c4 * 4];
    }
    __syncthreads();

    const int nl  = tid >> 5;   // node within block
    const int col = tid & 31;   // head column
    float acc = hb[col];
    const float4* up = (const float4*)&u_lds[nl][0];
    const float4* wp = (const float4*)&Wht[col][0];
#pragma unroll 8
    for (int k4 = 0; k4 < 32; ++k4) {
        const float4 u = up[k4], w = wp[k4];
        acc += u.x * w.x; acc += u.y * w.y; acc += u.z * w.z; acc += u.w * w.w;
    }
    float val = fmaxf(acc, 0.f) * w2[col];
#pragma unroll
    for (int off = 8; off >= 1; off >>= 1) val += __shfl_xor(val, off);
    const int node = node0 + nl;
    if (col == 0)  logits[node] = val + ba2[0];
    if (col == 16) crit[node]   = val + bc2[0];
}

// ---------------- per-graph finalize: log_prob, entropy, value, actions ----------------
__device__ __forceinline__ float blockRedMax(float v, float* red) {
#pragma unroll
    for (int o = 32; o >= 1; o >>= 1) v = fmaxf(v, __shfl_xor(v, o));
    const int w = threadIdx.x >> 6;
    __syncthreads();
    if ((threadIdx.x & 63) == 0) red[w] = v;
    __syncthreads();
    if (threadIdx.x < 16) {
        float x = red[threadIdx.x];
#pragma unroll
        for (int o = 8; o >= 1; o >>= 1) x = fmaxf(x, __shfl_xor(x, o));
        if (threadIdx.x == 0) red[0] = x;
    }
    __syncthreads();
    const float r = red[0];
    __syncthreads();
    return r;
}

__device__ __forceinline__ float blockRedSum(float v, float* red) {
#pragma unroll
    for (int o = 32; o >= 1; o >>= 1) v += __shfl_xor(v, o);
    const int w = threadIdx.x >> 6;
    __syncthreads();
    if ((threadIdx.x & 63) == 0) red[w] = v;
    __syncthreads();
    if (threadIdx.x < 16) {
        float x = red[threadIdx.x];
#pragma unroll
        for (int o = 8; o >= 1; o >>= 1) x += __shfl_xor(x, o);
        if (threadIdx.x == 0) red[0] = x;
    }
    __syncthreads();
    const float r = red[0];
    __syncthreads();
    return r;
}

__global__ __launch_bounds__(1024) void finalize_kernel(
    const float* __restrict__ logits, const float* __restrict__ crit,
    const int* __restrict__ actions, float* __restrict__ out, int NP, int G)
{
    __shared__ float slog[12512];   // NP <= 12512
    __shared__ float red[16];
    const int g = blockIdx.x;
    const int tid = threadIdx.x;
    const float* lg = logits + (long long)g * NP;
    const float* cg = crit   + (long long)g * NP;

    float lmax = -3.402823466e38f, cmax = -3.402823466e38f, csum = 0.f;
    for (int i = tid; i < NP; i += 1024) {
        const float l = lg[i], c = cg[i];
        slog[i] = l;
        lmax = fmaxf(lmax, l);
        cmax = fmaxf(cmax, c);
        csum += c;
    }
    __syncthreads();
    lmax = blockRedMax(lmax, red);
    cmax = blockRedMax(cmax, red);
    csum = blockRedSum(csum, red);

    float zsum = 0.f, ssum = 0.f;
    for (int i = tid; i < NP; i += 1024) {
        const float s = slog[i];
        const float e = expf(s - lmax);
        zsum += e;
        ssum += s * e;
    }
    zsum = blockRedSum(zsum, red);
    ssum = blockRedSum(ssum, red);

    if (tid == 0) {
        const int a = actions[g];
        const float sa   = slog[a];
        const float logZ = logf(zsum) + lmax;
        const float lp   = sa - logZ;
        const float H    = logZ - ssum / zsum;
        const float v    = cmax * 0.5f + (csum / (float)NP) * 0.5f;
        out[g]         = (float)a;   // actions echoed as float
        out[G + g]     = lp;
        out[2 * G + g] = H;
        out[3 * G + g] = v;
    }
}

extern "C" void kernel_launch(void* const* d_in, const int* in_sizes, int n_in,
                              void* d_out, int out_size, void* d_ws, size_t ws_size,
                              hipStream_t stream)
{
    const float* inputs = (const float*)d_in[0];
    const float* W_in   = (const float*)d_in[1];
    const float* b_in   = (const float*)d_in[2];
    const float* W_msg  = (const float*)d_in[3];
    const float* b_msg  = (const float*)d_in[4];
    const float* W_upd  = (const float*)d_in[5];
    const float* b_upd  = (const float*)d_in[6];
    const float* W_a1   = (const float*)d_in[7];
    const float* b_a1   = (const float*)d_in[8];
    const float* W_a2   = (const float*)d_in[9];
    const float* b_a2   = (const float*)d_in[10];
    const float* W_c1   = (const float*)d_in[11];
    const float* b_c1   = (const float*)d_in[12];
    const float* W_c2   = (const float*)d_in[13];
    const float* b_c2   = (const float*)d_in[14];
    const int* edge_src = (const int*)d_in[15];
    const int* edge_dst = (const int*)d_in[16];
    const int* actions  = (const int*)d_in[17];

    const int N  = in_sizes[0] / 128;
    const int E  = in_sizes[15];
    const int G  = in_sizes[17];
    const int NP = N / G;

    float* out         = (float*)d_out;
    float* node_states = out;                       // reuse updates region [N*128]

    // workspace layout
    float* msg    = (float*)d_ws;                   // [N*128]
    float* agg    = msg + (size_t)N * 128;          // [N*128]
    float* logits = agg + (size_t)N * 128;          // [N]
    float* crit   = logits + N;                     // [N]
    int*   counts = (int*)(crit + N);               // [N]
    int*   offs   = counts + N;                     // [N+1]
    int*   cursor = offs + (N + 1);                 // [N]
    int*   bsum   = cursor + N;                     // [256]
    int*   bpref  = bsum + 256;                     // [256]
    int*   csr    = bpref + 256;                    // [E]

    const int NB = (N + 1023) / 1024;               // chunks for scan (<= 256)

    hipMemsetAsync(counts, 0, (size_t)N * sizeof(int), stream);

    const int gemmGrid = (N + BM - 1) / BM;
    const int egrid    = (E + 255) / 256;

    // node_states = relu(inputs @ W_in + b_in)  -> d_out region
    gemm_relu_kernel<<<gemmGrid, 256, 0, stream>>>(inputs, nullptr, 128, 128, W_in, b_in, node_states, N);
    // CSR build (overlaps conceptually; stream-serial is fine)
    count_edges_kernel<<<egrid, 256, 0, stream>>>(edge_dst, counts, E);
    block_reduce_kernel<<<NB, 256, 0, stream>>>(counts, bsum, N);
    scan_sums_kernel<<<1, 256, 0, stream>>>(bsum, bpref, NB, offs, N, E);
    scan_apply_kernel<<<NB, 256, 0, stream>>>(counts, bpref, offs, cursor, N);
    fill_csr_kernel<<<egrid, 256, 0, stream>>>(edge_src, edge_dst, cursor, csr, E);
    // messages = relu(node_states @ W_msg + b_msg)
    gemm_relu_kernel<<<gemmGrid, 256, 0, stream>>>(node_states, nullptr, 128, 128, W_msg, b_msg, msg, N);
    // agg = segment_sum via CSR gather (no f32 atomics)
    gather_kernel<<<(N + 7) / 8, 256, 0, stream>>>(offs, csr, msg, agg, N);
    // updates = relu([agg | node_states] @ W_upd + b_upd)  -> in-place over node_states in d_out
    gemm_relu_kernel<<<gemmGrid, 256, 0, stream>>>(agg, node_states, 128, 256, W_upd, b_upd, out, N);
    // heads
    head_kernel<<<N / 8, 256, 0, stream>>>(out, W_a1, b_a1, W_a2, b_a2, W_c1, b_c1, W_c2, b_c2, logits, crit);
    // per-graph outputs
    finalize_kernel<<<G, 1024, 0, stream>>>(logits, crit, actions, out + (size_t)N * 128, NP, G);
}

// Round 5
// 486.976 us; speedup vs baseline: 6.2024x; 1.2939x over previous
//
#include <hip/hip_runtime.h>
#include <math.h>

// ---------------- GEMM: C[rows][128] = relu(concat(A1,A2)[rows][Ktot] @ W[Ktot][128] + bias) ----------------
#define BM 64
#define KC 32

__global__ __launch_bounds__(256) void gemm_relu_kernel(
    const float* __restrict__ A1, const float* __restrict__ A2,
    int K1, int Ktot,
    const float* __restrict__ W, const float* __restrict__ bias,
    float* __restrict__ C, int rows)
{
    __shared__ float At[KC][BM + 4];   // A chunk, transposed: At[k][row]
    __shared__ float Ws[KC][128];      // W chunk
    const int tid  = threadIdx.x;
    const int row0 = blockIdx.x * BM;
    const int trow = tid >> 4;   // 0..15 -> rows trow*4 .. trow*4+3
    const int tcol = tid & 15;   // 0..15 -> cols tcol*4..+3 and 64+tcol*4..+3

    float acc[4][8];
#pragma unroll
    for (int r = 0; r < 4; ++r)
#pragma unroll
        for (int c = 0; c < 8; ++c) acc[r][c] = 0.f;

    for (int k0 = 0; k0 < Ktot; k0 += KC) {
        const float* A; int ka, lda;
        if (k0 < K1) { A = A1; ka = k0;      lda = K1; }
        else         { A = A2; ka = k0 - K1; lda = Ktot - K1; }

        // stage A chunk transposed: 64 rows x 32 k
        {
            const int kk = tid & 31;
            const int i0 = tid >> 5;  // 0..7
#pragma unroll
            for (int p = 0; p < 8; ++p) {
                const int i  = i0 + p * 8;
                const int gr = row0 + i;
                At[kk][i] = (gr < rows) ? A[(long long)gr * lda + ka + kk] : 0.f;
            }
        }
        // stage W chunk: 32 x 128 (float4)
        {
#pragma unroll
            for (int p = 0; p < 4; ++p) {
                const int f4 = tid + p * 256;          // 0..1023
                const int r  = f4 >> 5, c4 = f4 & 31;
                *(float4*)&Ws[r][c4 * 4] =
                    *(const float4*)&W[(long long)(k0 + r) * 128 + c4 * 4];
            }
        }
        __syncthreads();

#pragma unroll 8
        for (int kk = 0; kk < KC; ++kk) {
            const float4 a  = *(const float4*)&At[kk][trow * 4];
            const float4 w0 = *(const float4*)&Ws[kk][tcol * 4];
            const float4 w1 = *(const float4*)&Ws[kk][64 + tcol * 4];
            const float av[4] = {a.x, a.y, a.z, a.w};
            const float wv[8] = {w0.x, w0.y, w0.z, w0.w, w1.x, w1.y, w1.z, w1.w};
#pragma unroll
            for (int r = 0; r < 4; ++r)
#pragma unroll
                for (int c = 0; c < 8; ++c) acc[r][c] += av[r] * wv[c];
        }
        __syncthreads();
    }

    // epilogue: bias + relu + store
#pragma unroll
    for (int r = 0; r < 4; ++r) {
        const int gr = row0 + trow * 4 + r;
        if (gr >= rows) continue;
        float4 o0, o1;
        o0.x = fmaxf(acc[r][0] + bias[tcol * 4 + 0], 0.f);
        o0.y = fmaxf(acc[r][1] + bias[tcol * 4 + 1], 0.f);
        o0.z = fmaxf(acc[r][2] + bias[tcol * 4 + 2], 0.f);
        o0.w = fmaxf(acc[r][3] + bias[tcol * 4 + 3], 0.f);
        o1.x = fmaxf(acc[r][4] + bias[64 + tcol * 4 + 0], 0.f);
        o1.y = fmaxf(acc[r][5] + bias[64 + tcol * 4 + 1], 0.f);
        o1.z = fmaxf(acc[r][6] + bias[64 + tcol * 4 + 2], 0.f);
        o1.w = fmaxf(acc[r][7] + bias[64 + tcol * 4 + 3], 0.f);
        *(float4*)&C[(long long)gr * 128 + tcol * 4]      = o0;
        *(float4*)&C[(long long)gr * 128 + 64 + tcol * 4] = o1;
    }
}

// ---------------- CSR build via two-pass LDS-binned counting sort ----------------
// Buckets of NPB=256 consecutive dst nodes. Pass A bins edges bucket-contiguously
// (packed (src<<8)|local_dst). Pass B builds per-node offsets + csr within each
// bucket using LDS histograms; csr writes stay inside an L2-resident ~16KB window.
#define NPB        256
#define NPB_SHIFT  8
#define EBUF_CAP   4608    // mean bucket load 4096, sigma~64 -> 8-sigma slack
#define MAX_BUK    512

__global__ __launch_bounds__(256) void bin_edges_kernel(
    const int* __restrict__ src, const int* __restrict__ dst,
    int* __restrict__ bcursor, int* __restrict__ ebuf,
    int E, int nbuk, int chunk)
{
    __shared__ int lcount[MAX_BUK];
    __shared__ int lbase[MAX_BUK];
    const int tid = threadIdx.x;
    const int e0 = blockIdx.x * chunk;
    const int e1 = min(e0 + chunk, E);
    for (int b = tid; b < nbuk; b += 256) lcount[b] = 0;
    __syncthreads();
    for (int i = e0 + tid; i < e1; i += 256)
        atomicAdd(&lcount[dst[i] >> NPB_SHIFT], 1);
    __syncthreads();
    for (int b = tid; b < nbuk; b += 256) {
        const int c = lcount[b];
        lbase[b] = c ? atomicAdd(&bcursor[b], c) : 0;
        lcount[b] = 0;
    }
    __syncthreads();
    for (int i = e0 + tid; i < e1; i += 256) {
        const int d = dst[i];
        const int b = d >> NPB_SHIFT;
        const int p = lbase[b] + atomicAdd(&lcount[b], 1);
        ebuf[b * EBUF_CAP + min(p, EBUF_CAP - 1)] = (src[i] << NPB_SHIFT) | (d & (NPB - 1));
    }
}

// exclusive scan of bucket counts -> ebase; also offs[N] = E
__global__ __launch_bounds__(1024) void scan_buckets_kernel(
    const int* __restrict__ bcursor, int* __restrict__ ebase,
    int nbuk, int* __restrict__ offs, int N, int E)
{
    __shared__ int ws[16], wp[16];
    const int t = threadIdx.x;
    const int v = (t < nbuk) ? bcursor[t] : 0;
    const int lane = t & 63, wid = t >> 6;
    int x = v;
#pragma unroll
    for (int off = 1; off < 64; off <<= 1) {
        const int y = __shfl_up(x, off);
        if (lane >= off) x += y;
    }
    if (lane == 63) ws[wid] = x;
    __syncthreads();
    if (t == 0) { int s = 0; for (int w = 0; w < 16; ++w) { wp[w] = s; s += ws[w]; } }
    __syncthreads();
    if (t < nbuk) ebase[t] = x - v + wp[wid];
    if (t == 0) offs[N] = E;
}

// one block per bucket: LDS histogram + scan + scatter into csr window
__global__ __launch_bounds__(256) void build_csr_kernel(
    const int* __restrict__ ebuf, const int* __restrict__ bcursor,
    const int* __restrict__ ebase,
    int* __restrict__ offs, int* __restrict__ csr, int N)
{
    __shared__ int ndeg[NPB];
    __shared__ int nofs[NPB];
    __shared__ int ws[4], wp[4];
    const int b   = blockIdx.x;
    const int tid = threadIdx.x;
    const int cnt  = min(bcursor[b], EBUF_CAP);
    const int base = ebase[b];
    const int* eb = ebuf + b * EBUF_CAP;

    ndeg[tid] = 0;
    __syncthreads();
    for (int j = tid; j < cnt; j += 256)
        atomicAdd(&ndeg[eb[j] & (NPB - 1)], 1);
    __syncthreads();

    // exclusive scan of ndeg[256]
    const int lane = tid & 63, wid = tid >> 6;
    const int v = ndeg[tid];
    int x = v;
#pragma unroll
    for (int off = 1; off < 64; off <<= 1) {
        const int y = __shfl_up(x, off);
        if (lane >= off) x += y;
    }
    if (lane == 63) ws[wid] = x;
    __syncthreads();
    if (tid == 0) { int s = 0; for (int w = 0; w < 4; ++w) { wp[w] = s; s += ws[w]; } }
    __syncthreads();
    const int excl = x - v + wp[wid];
    nofs[tid] = excl;
    const int node = (b << NPB_SHIFT) + tid;
    if (node < N) offs[node] = base + excl;
    ndeg[tid] = 0;
    __syncthreads();

    for (int j = tid; j < cnt; j += 256) {
        const int e = eb[j];
        const int d = e & (NPB - 1);
        const int p = atomicAdd(&ndeg[d], 1);
        csr[base + nofs[d] + p] = e >> NPB_SHIFT;
    }
}

// ---------------- gather: agg[n] = sum over in-edges of msg[src] ----------------
__global__ __launch_bounds__(256) void gather_kernel(
    const int* __restrict__ offs, const int* __restrict__ csr,
    const float* __restrict__ msg, float* __restrict__ agg, int N)
{
    const int node = blockIdx.x * 8 + (threadIdx.x >> 5);
    if (node >= N) return;
    const int c4 = threadIdx.x & 31;
    const int j1 = offs[node + 1];
    int j = offs[node];
    const float4* mv = (const float4*)msg;
    float4 acc = make_float4(0.f, 0.f, 0.f, 0.f);
    for (; j + 1 < j1; j += 2) {
        const int s0 = csr[j], s1 = csr[j + 1];
        const float4 a = mv[(long long)s0 * 32 + c4];
        const float4 b = mv[(long long)s1 * 32 + c4];
        acc.x += a.x; acc.y += a.y; acc.z += a.z; acc.w += a.w;
        acc.x += b.x; acc.y += b.y; acc.z += b.z; acc.w += b.w;
    }
    if (j < j1) {
        const int s = csr[j];
        const float4 a = mv[(long long)s * 32 + c4];
        acc.x += a.x; acc.y += a.y; acc.z += a.z; acc.w += a.w;
    }
    ((float4*)agg)[(long long)node * 32 + c4] = acc;
}

// ---------------- actor/critic heads: logits[N], crit[N] ----------------
__global__ __launch_bounds__(256) void head_kernel(
    const float* __restrict__ U,
    const float* __restrict__ Wa1, const float* __restrict__ ba1,
    const float* __restrict__ Wa2, const float* __restrict__ ba2,
    const float* __restrict__ Wc1, const float* __restrict__ bc1,
    const float* __restrict__ Wc2, const float* __restrict__ bc2,
    float* __restrict__ logits, float* __restrict__ crit)
{
    __shared__ float Wht[32][132];   // transposed: Wht[col][k], cols 0-15 actor, 16-31 critic
    __shared__ float u_lds[8][132];
    __shared__ float w2[32], hb[32];
    const int tid = threadIdx.x;

    for (int idx = tid; idx < 4096; idx += 256) {
        const int k = idx & 127, col = idx >> 7;
        Wht[col][k] = (col < 16) ? Wa1[k * 16 + col] : Wc1[k * 16 + (col - 16)];
    }
    if (tid < 32) {
        w2[tid] = (tid < 16) ? Wa2[tid] : Wc2[tid - 16];
        hb[tid] = (tid < 16) ? ba1[tid] : bc1[tid - 16];
    }
    const int node0 = blockIdx.x * 8;
    {
        const int row = tid >> 5, c4 = tid & 31;
        *(float4*)&u_lds[row][c4 * 4] =
            *(const float4*)&U[(long long)(node0 + row) * 128 + c4 * 4];
    }
    __syncthreads();

    const int nl  = tid >> 5;   // node within block
    const int col = tid & 31;   // head column
    float acc = hb[col];
    const float4* up = (const float4*)&u_lds[nl][0];
    const float4* wp = (const float4*)&Wht[col][0];
#pragma unroll 8
    for (int k4 = 0; k4 < 32; ++k4) {
        const float4 u = up[k4], w = wp[k4];
        acc += u.x * w.x; acc += u.y * w.y; acc += u.z * w.z; acc += u.w * w.w;
    }
    float val = fmaxf(acc, 0.f) * w2[col];
#pragma unroll
    for (int off = 8; off >= 1; off >>= 1) val += __shfl_xor(val, off);
    const int node = node0 + nl;
    if (col == 0)  logits[node] = val + ba2[0];
    if (col == 16) crit[node]   = val + bc2[0];
}

// ---------------- per-graph finalize: log_prob, entropy, value, actions ----------------
__device__ __forceinline__ float blockRedMax(float v, float* red) {
#pragma unroll
    for (int o = 32; o >= 1; o >>= 1) v = fmaxf(v, __shfl_xor(v, o));
    const int w = threadIdx.x >> 6;
    __syncthreads();
    if ((threadIdx.x & 63) == 0) red[w] = v;
    __syncthreads();
    if (threadIdx.x < 16) {
        float x = red[threadIdx.x];
#pragma unroll
        for (int o = 8; o >= 1; o >>= 1) x = fmaxf(x, __shfl_xor(x, o));
        if (threadIdx.x == 0) red[0] = x;
    }
    __syncthreads();
    const float r = red[0];
    __syncthreads();
    return r;
}

__device__ __forceinline__ float blockRedSum(float v, float* red) {
#pragma unroll
    for (int o = 32; o >= 1; o >>= 1) v += __shfl_xor(v, o);
    const int w = threadIdx.x >> 6;
    __syncthreads();
    if ((threadIdx.x & 63) == 0) red[w] = v;
    __syncthreads();
    if (threadIdx.x < 16) {
        float x = red[threadIdx.x];
#pragma unroll
        for (int o = 8; o >= 1; o >>= 1) x += __shfl_xor(x, o);
        if (threadIdx.x == 0) red[0] = x;
    }
    __syncthreads();
    const float r = red[0];
    __syncthreads();
    return r;
}

__global__ __launch_bounds__(1024) void finalize_kernel(
    const float* __restrict__ logits, const float* __restrict__ crit,
    const int* __restrict__ actions, float* __restrict__ out, int NP, int G)
{
    __shared__ float slog[12512];   // NP <= 12512
    __shared__ float red[16];
    const int g = blockIdx.x;
    const int tid = threadIdx.x;
    const float* lg = logits + (long long)g * NP;
    const float* cg = crit   + (long long)g * NP;

    float lmax = -3.402823466e38f, cmax = -3.402823466e38f, csum = 0.f;
    for (int i = tid; i < NP; i += 1024) {
        const float l = lg[i], c = cg[i];
        slog[i] = l;
        lmax = fmaxf(lmax, l);
        cmax = fmaxf(cmax, c);
        csum += c;
    }
    __syncthreads();
    lmax = blockRedMax(lmax, red);
    cmax = blockRedMax(cmax, red);
    csum = blockRedSum(csum, red);

    float zsum = 0.f, ssum = 0.f;
    for (int i = tid; i < NP; i += 1024) {
        const float s = slog[i];
        const float e = expf(s - lmax);
        zsum += e;
        ssum += s * e;
    }
    zsum = blockRedSum(zsum, red);
    ssum = blockRedSum(ssum, red);

    if (tid == 0) {
        const int a = actions[g];
        const float sa   = slog[a];
        const float logZ = logf(zsum) + lmax;
        const float lp   = sa - logZ;
        const float H    = logZ - ssum / zsum;
        const float v    = cmax * 0.5f + (csum / (float)NP) * 0.5f;
        out[g]         = (float)a;   // actions echoed as float
        out[G + g]     = lp;
        out[2 * G + g] = H;
        out[3 * G + g] = v;
    }
}

extern "C" void kernel_launch(void* const* d_in, const int* in_sizes, int n_in,
                              void* d_out, int out_size, void* d_ws, size_t ws_size,
                              hipStream_t stream)
{
    const float* inputs = (const float*)d_in[0];
    const float* W_in   = (const float*)d_in[1];
    const float* b_in   = (const float*)d_in[2];
    const float* W_msg  = (const float*)d_in[3];
    const float* b_msg  = (const float*)d_in[4];
    const float* W_upd  = (const float*)d_in[5];
    const float* b_upd  = (const float*)d_in[6];
    const float* W_a1   = (const float*)d_in[7];
    const float* b_a1   = (const float*)d_in[8];
    const float* W_a2   = (const float*)d_in[9];
    const float* b_a2   = (const float*)d_in[10];
    const float* W_c1   = (const float*)d_in[11];
    const float* b_c1   = (const float*)d_in[12];
    const float* W_c2   = (const float*)d_in[13];
    const float* b_c2   = (const float*)d_in[14];
    const int* edge_src = (const int*)d_in[15];
    const int* edge_dst = (const int*)d_in[16];
    const int* actions  = (const int*)d_in[17];

    const int N  = in_sizes[0] / 128;
    const int E  = in_sizes[15];
    const int G  = in_sizes[17];
    const int NP = N / G;
    const int nbuk = (N + NPB - 1) >> NPB_SHIFT;

    float* out         = (float*)d_out;
    float* node_states = out;                       // reuse updates region [N*128]

    // workspace layout
    float* msg     = (float*)d_ws;                  // [N*128]
    float* agg     = msg + (size_t)N * 128;         // [N*128]
    float* logits  = agg + (size_t)N * 128;         // [N]
    float* crit    = logits + N;                    // [N]
    int*   offs    = (int*)(crit + N);              // [N+1]
    int*   csr     = offs + (N + 1);                // [E]
    int*   bcursor = csr + E;                       // [nbuk]
    int*   ebase   = bcursor + MAX_BUK;             // [nbuk]
    int*   ebuf    = ebase + MAX_BUK;               // [nbuk * EBUF_CAP]

    hipMemsetAsync(bcursor, 0, (size_t)nbuk * sizeof(int), stream);

    const int gemmGrid = (N + BM - 1) / BM;
    const int chunk = 4096;
    const int binGrid = (E + chunk - 1) / chunk;

    // node_states = relu(inputs @ W_in + b_in)  -> d_out region
    gemm_relu_kernel<<<gemmGrid, 256, 0, stream>>>(inputs, nullptr, 128, 128, W_in, b_in, node_states, N);
    // CSR build (two-pass LDS counting sort)
    bin_edges_kernel<<<binGrid, 256, 0, stream>>>(edge_src, edge_dst, bcursor, ebuf, E, nbuk, chunk);
    scan_buckets_kernel<<<1, 1024, 0, stream>>>(bcursor, ebase, nbuk, offs, N, E);
    build_csr_kernel<<<nbuk, 256, 0, stream>>>(ebuf, bcursor, ebase, offs, csr, N);
    // messages = relu(node_states @ W_msg + b_msg)
    gemm_relu_kernel<<<gemmGrid, 256, 0, stream>>>(node_states, nullptr, 128, 128, W_msg, b_msg, msg, N);
    // agg = segment_sum via CSR gather (no f32 atomics)
    gather_kernel<<<(N + 7) / 8, 256, 0, stream>>>(offs, csr, msg, agg, N);
    // updates = relu([agg | node_states] @ W_upd + b_upd)  -> in-place over node_states in d_out
    gemm_relu_kernel<<<gemmGrid, 256, 0, stream>>>(agg, node_states, 128, 256, W_upd, b_upd, out, N);
    // heads
    head_kernel<<<N / 8, 256, 0, stream>>>(out, W_a1, b_a1, W_a2, b_a2, W_c1, b_c1, W_c2, b_c2, logits, crit);
    // per-graph outputs
    finalize_kernel<<<G, 1024, 0, stream>>>(logits, crit, actions, out + (size_t)N * 128, NP, G);
}

// Round 6
// 302.629 us; speedup vs baseline: 9.9806x; 1.6091x over previous
//
#include <hip/hip_runtime.h>
#include <math.h>

typedef unsigned short u16;
typedef unsigned int   u32;
typedef __attribute__((ext_vector_type(8))) short short8v;
typedef __attribute__((ext_vector_type(4))) float f32x4;

__device__ __forceinline__ u16 f2bf(float x) {
    u32 u = __float_as_uint(x);
    u += 0x7FFFu + ((u >> 16) & 1u);   // RNE
    return (u16)(u >> 16);
}
__device__ __forceinline__ float bf_lo(u32 u) { return __uint_as_float(u << 16); }
__device__ __forceinline__ float bf_hi(u32 u) { return __uint_as_float(u & 0xFFFF0000u); }

// ---------------- convert inputs f32 -> bf16 (8 elems/thread) ----------------
__global__ __launch_bounds__(256) void convert_inputs_kernel(
    const float* __restrict__ x, u16* __restrict__ y, long long n8)
{
    const long long i = (long long)blockIdx.x * 256 + threadIdx.x;
    if (i >= n8) return;
    const float4 a = ((const float4*)x)[i * 2 + 0];
    const float4 b = ((const float4*)x)[i * 2 + 1];
    u16 r[8] = {f2bf(a.x), f2bf(a.y), f2bf(a.z), f2bf(a.w),
                f2bf(b.x), f2bf(b.y), f2bf(b.z), f2bf(b.w)};
    ((uint4*)y)[i] = *(uint4*)r;
}

// ---------------- convert+transpose weight: W[K][128] f32 -> Wt[128][K] bf16 ----------------
__global__ __launch_bounds__(256) void convert_w_kernel(
    const float* __restrict__ W, u16* __restrict__ Wt, int K)
{
    for (int idx = blockIdx.x * 256 + threadIdx.x; idx < 128 * K; idx += gridDim.x * 256) {
        const int c = idx / K, k = idx - c * K;
        Wt[idx] = f2bf(W[k * 128 + c]);
    }
}

// ---------------- MFMA GEMM: C[rows][128] = relu(concat(A1,A2)[rows][K] @ W + bias) ----------------
// A1,A2: bf16, row length 128 each (A2 used for k>=128 when K==256).
// Wt: [128 cols][K] bf16 (pre-transposed). Output f32 (Cf) or bf16 (Cb).
template<int K, bool OUT_F32>
__global__ __launch_bounds__(256) void mfma_gemm_kernel(
    const u16* __restrict__ A1, const u16* __restrict__ A2,
    const u16* __restrict__ Wt, const float* __restrict__ bias,
    float* __restrict__ Cf, u16* __restrict__ Cb, int rows)
{
    constexpr int KS  = K / 32;        // k-steps
    constexpr int LDW = K + 8;         // +8 bf16 pad: 16B-aligned rows, bank-spread
    __shared__ u16 WtL[128][LDW];

    const int tid = threadIdx.x;
    // stage Wt -> LDS (uint4 = 8 bf16)
    const int nu4 = 128 * K / 8;
    for (int i = tid; i < nu4; i += 256) {
        const int row = i / (K / 8), k8 = i - row * (K / 8);
        *(uint4*)&WtL[row][k8 * 8] = ((const uint4*)Wt)[i];
    }

    const int lane = tid & 63, wave = tid >> 6;
    const int lrow = lane & 15, lk = lane >> 4;
    const int r0   = blockIdx.x * 64 + wave * 16;
    const int arow = r0 + lrow;
    const bool rowok = arow < rows;

    // A fragments: lane holds row (lane&15), k = ks*32 + (lane>>4)*8 + {0..7}
    short8v a[KS];
#pragma unroll
    for (int ks = 0; ks < KS; ++ks) {
        const int k = ks * 32 + lk * 8;
        const u16* p = (K == 256 && k >= 128) ? (A2 + (size_t)arow * 128 + (k - 128))
                                              : (A1 + (size_t)arow * 128 + k);
        short8v av = {};
        if (rowok) av = *(const short8v*)p;
        a[ks] = av;
    }
    float bcol[8];
#pragma unroll
    for (int n = 0; n < 8; ++n) bcol[n] = bias[n * 16 + lrow];

    __syncthreads();

    f32x4 acc[8];
#pragma unroll
    for (int n = 0; n < 8; ++n) acc[n] = (f32x4){0.f, 0.f, 0.f, 0.f};

#pragma unroll
    for (int ks = 0; ks < KS; ++ks) {
#pragma unroll
        for (int n = 0; n < 8; ++n) {
            const short8v b = *(const short8v*)&WtL[n * 16 + lrow][ks * 32 + lk * 8];
            acc[n] = __builtin_amdgcn_mfma_f32_16x16x32_bf16(a[ks], b, acc[n], 0, 0, 0);
        }
    }

    // epilogue: C/D layout col = lane&15, row = 4*(lane>>4) + reg
#pragma unroll
    for (int reg = 0; reg < 4; ++reg) {
        const int row = r0 + lk * 4 + reg;
        if (row >= rows) continue;
#pragma unroll
        for (int n = 0; n < 8; ++n) {
            const float v = fmaxf(acc[n][reg] + bcol[n], 0.f);
            const size_t o = (size_t)row * 128 + n * 16 + lrow;
            if (OUT_F32) Cf[o] = v;
            else         Cb[o] = f2bf(v);
        }
    }
}

// ---------------- CSR build via two-pass LDS-binned counting sort ----------------
#define NPB        256
#define NPB_SHIFT  8
#define EBUF_CAP   4608
#define MAX_BUK    512

__global__ __launch_bounds__(256) void bin_edges_kernel(
    const int* __restrict__ src, const int* __restrict__ dst,
    int* __restrict__ bcursor, int* __restrict__ ebuf,
    int E, int nbuk, int chunk)
{
    __shared__ int lcount[MAX_BUK];
    __shared__ int lbase[MAX_BUK];
    const int tid = threadIdx.x;
    const int e0 = blockIdx.x * chunk;
    const int e1 = min(e0 + chunk, E);
    for (int b = tid; b < nbuk; b += 256) lcount[b] = 0;
    __syncthreads();
    for (int i = e0 + tid; i < e1; i += 256)
        atomicAdd(&lcount[dst[i] >> NPB_SHIFT], 1);
    __syncthreads();
    for (int b = tid; b < nbuk; b += 256) {
        const int c = lcount[b];
        lbase[b] = c ? atomicAdd(&bcursor[b], c) : 0;
        lcount[b] = 0;
    }
    __syncthreads();
    for (int i = e0 + tid; i < e1; i += 256) {
        const int d = dst[i];
        const int b = d >> NPB_SHIFT;
        const int p = lbase[b] + atomicAdd(&lcount[b], 1);
        ebuf[b * EBUF_CAP + min(p, EBUF_CAP - 1)] = (src[i] << NPB_SHIFT) | (d & (NPB - 1));
    }
}

__global__ __launch_bounds__(1024) void scan_buckets_kernel(
    const int* __restrict__ bcursor, int* __restrict__ ebase,
    int nbuk, int* __restrict__ offs, int N, int E)
{
    __shared__ int ws[16], wp[16];
    const int t = threadIdx.x;
    const int v = (t < nbuk) ? bcursor[t] : 0;
    const int lane = t & 63, wid = t >> 6;
    int x = v;
#pragma unroll
    for (int off = 1; off < 64; off <<= 1) {
        const int y = __shfl_up(x, off);
        if (lane >= off) x += y;
    }
    if (lane == 63) ws[wid] = x;
    __syncthreads();
    if (t == 0) { int s = 0; for (int w = 0; w < 16; ++w) { wp[w] = s; s += ws[w]; } }
    __syncthreads();
    if (t < nbuk) ebase[t] = x - v + wp[wid];
    if (t == 0) offs[N] = E;
}

__global__ __launch_bounds__(256) void build_csr_kernel(
    const int* __restrict__ ebuf, const int* __restrict__ bcursor,
    const int* __restrict__ ebase,
    int* __restrict__ offs, int* __restrict__ csr, int N)
{
    __shared__ int ndeg[NPB];
    __shared__ int nofs[NPB];
    __shared__ int ws[4], wp[4];
    const int b   = blockIdx.x;
    const int tid = threadIdx.x;
    const int cnt  = min(bcursor[b], EBUF_CAP);
    const int base = ebase[b];
    const int* eb = ebuf + b * EBUF_CAP;

    ndeg[tid] = 0;
    __syncthreads();
    for (int j = tid; j < cnt; j += 256)
        atomicAdd(&ndeg[eb[j] & (NPB - 1)], 1);
    __syncthreads();

    const int lane = tid & 63, wid = tid >> 6;
    const int v = ndeg[tid];
    int x = v;
#pragma unroll
    for (int off = 1; off < 64; off <<= 1) {
        const int y = __shfl_up(x, off);
        if (lane >= off) x += y;
    }
    if (lane == 63) ws[wid] = x;
    __syncthreads();
    if (tid == 0) { int s = 0; for (int w = 0; w < 4; ++w) { wp[w] = s; s += ws[w]; } }
    __syncthreads();
    const int excl = x - v + wp[wid];
    nofs[tid] = excl;
    const int node = (b << NPB_SHIFT) + tid;
    if (node < N) offs[node] = base + excl;
    ndeg[tid] = 0;
    __syncthreads();

    for (int j = tid; j < cnt; j += 256) {
        const int e = eb[j];
        const int d = e & (NPB - 1);
        const int p = atomicAdd(&ndeg[d], 1);
        csr[base + nofs[d] + p] = e >> NPB_SHIFT;
    }
}

// ---------------- gather (bf16): agg[n] = sum over in-edges of msg[src] ----------------
__global__ __launch_bounds__(256) void gather_bf16_kernel(
    const int* __restrict__ offs, const int* __restrict__ csr,
    const u16* __restrict__ msg, u16* __restrict__ agg, int N)
{
    const int node = blockIdx.x * 16 + (threadIdx.x >> 4);
    if (node >= N) return;
    const int c8 = threadIdx.x & 15;      // which 16B (8 bf16) chunk of the 128-wide row
    int j = offs[node];
    const int j1 = offs[node + 1];
    const uint4* mv = (const uint4*)msg;
    float acc[8] = {0.f, 0.f, 0.f, 0.f, 0.f, 0.f, 0.f, 0.f};
    for (; j + 1 < j1; j += 2) {
        const int s0 = csr[j], s1 = csr[j + 1];
        const uint4 u = mv[(size_t)s0 * 16 + c8];
        const uint4 v = mv[(size_t)s1 * 16 + c8];
        acc[0] += bf_lo(u.x); acc[1] += bf_hi(u.x);
        acc[2] += bf_lo(u.y); acc[3] += bf_hi(u.y);
        acc[4] += bf_lo(u.z); acc[5] += bf_hi(u.z);
        acc[6] += bf_lo(u.w); acc[7] += bf_hi(u.w);
        acc[0] += bf_lo(v.x); acc[1] += bf_hi(v.x);
        acc[2] += bf_lo(v.y); acc[3] += bf_hi(v.y);
        acc[4] += bf_lo(v.z); acc[5] += bf_hi(v.z);
        acc[6] += bf_lo(v.w); acc[7] += bf_hi(v.w);
    }
    if (j < j1) {
        const uint4 u = mv[(size_t)csr[j] * 16 + c8];
        acc[0] += bf_lo(u.x); acc[1] += bf_hi(u.x);
        acc[2] += bf_lo(u.y); acc[3] += bf_hi(u.y);
        acc[4] += bf_lo(u.z); acc[5] += bf_hi(u.z);
        acc[6] += bf_lo(u.w); acc[7] += bf_hi(u.w);
    }
    u16 r[8];
#pragma unroll
    for (int q = 0; q < 8; ++q) r[q] = f2bf(acc[q]);
    ((uint4*)agg)[(size_t)node * 16 + c8] = *(uint4*)r;
}

// ---------------- actor/critic heads: logits[N], crit[N] ----------------
__global__ __launch_bounds__(256) void head_kernel(
    const float* __restrict__ U,
    const float* __restrict__ Wa1, const float* __restrict__ ba1,
    const float* __restrict__ Wa2, const float* __restrict__ ba2,
    const float* __restrict__ Wc1, const float* __restrict__ bc1,
    const float* __restrict__ Wc2, const float* __restrict__ bc2,
    float* __restrict__ logits, float* __restrict__ crit)
{
    __shared__ float Wht[32][132];
    __shared__ float u_lds[8][132];
    __shared__ float w2[32], hb[32];
    const int tid = threadIdx.x;

    for (int idx = tid; idx < 4096; idx += 256) {
        const int k = idx & 127, col = idx >> 7;
        Wht[col][k] = (col < 16) ? Wa1[k * 16 + col] : Wc1[k * 16 + (col - 16)];
    }
    if (tid < 32) {
        w2[tid] = (tid < 16) ? Wa2[tid] : Wc2[tid - 16];
        hb[tid] = (tid < 16) ? ba1[tid] : bc1[tid - 16];
    }
    const int node0 = blockIdx.x * 8;
    {
        const int row = tid >> 5, c4 = tid & 31;
        *(float4*)&u_lds[row][c4 * 4] =
            *(const float4*)&U[(long long)(node0 + row) * 128 + c4 * 4];
    }
    __syncthreads();

    const int nl  = tid >> 5;
    const int col = tid & 31;
    float acc = hb[col];
    const float4* up = (const float4*)&u_lds[nl][0];
    const float4* wp = (const float4*)&Wht[col][0];
#pragma unroll 8
    for (int k4 = 0; k4 < 32; ++k4) {
        const float4 u = up[k4], w = wp[k4];
        acc += u.x * w.x; acc += u.y * w.y; acc += u.z * w.z; acc += u.w * w.w;
    }
    float val = fmaxf(acc, 0.f) * w2[col];
#pragma unroll
    for (int off = 8; off >= 1; off >>= 1) val += __shfl_xor(val, off);
    const int node = node0 + nl;
    if (col == 0)  logits[node] = val + ba2[0];
    if (col == 16) crit[node]   = val + bc2[0];
}

// ---------------- per-graph finalize ----------------
__device__ __forceinline__ float blockRedMax(float v, float* red) {
#pragma unroll
    for (int o = 32; o >= 1; o >>= 1) v = fmaxf(v, __shfl_xor(v, o));
    const int w = threadIdx.x >> 6;
    __syncthreads();
    if ((threadIdx.x & 63) == 0) red[w] = v;
    __syncthreads();
    if (threadIdx.x < 16) {
        float x = red[threadIdx.x];
#pragma unroll
        for (int o = 8; o >= 1; o >>= 1) x = fmaxf(x, __shfl_xor(x, o));
        if (threadIdx.x == 0) red[0] = x;
    }
    __syncthreads();
    const float r = red[0];
    __syncthreads();
    return r;
}

__device__ __forceinline__ float blockRedSum(float v, float* red) {
#pragma unroll
    for (int o = 32; o >= 1; o >>= 1) v += __shfl_xor(v, o);
    const int w = threadIdx.x >> 6;
    __syncthreads();
    if ((threadIdx.x & 63) == 0) red[w] = v;
    __syncthreads();
    if (threadIdx.x < 16) {
        float x = red[threadIdx.x];
#pragma unroll
        for (int o = 8; o >= 1; o >>= 1) x += __shfl_xor(x, o);
        if (threadIdx.x == 0) red[0] = x;
    }
    __syncthreads();
    const float r = red[0];
    __syncthreads();
    return r;
}

__global__ __launch_bounds__(1024) void finalize_kernel(
    const float* __restrict__ logits, const float* __restrict__ crit,
    const int* __restrict__ actions, float* __restrict__ out, int NP, int G)
{
    __shared__ float slog[12512];
    __shared__ float red[16];
    const int g = blockIdx.x;
    const int tid = threadIdx.x;
    const float* lg = logits + (long long)g * NP;
    const float* cg = crit   + (long long)g * NP;

    float lmax = -3.402823466e38f, cmax = -3.402823466e38f, csum = 0.f;
    for (int i = tid; i < NP; i += 1024) {
        const float l = lg[i], c = cg[i];
        slog[i] = l;
        lmax = fmaxf(lmax, l);
        cmax = fmaxf(cmax, c);
        csum += c;
    }
    __syncthreads();
    lmax = blockRedMax(lmax, red);
    cmax = blockRedMax(cmax, red);
    csum = blockRedSum(csum, red);

    float zsum = 0.f, ssum = 0.f;
    for (int i = tid; i < NP; i += 1024) {
        const float s = slog[i];
        const float e = expf(s - lmax);
        zsum += e;
        ssum += s * e;
    }
    zsum = blockRedSum(zsum, red);
    ssum = blockRedSum(ssum, red);

    if (tid == 0) {
        const int a = actions[g];
        const float sa   = slog[a];
        const float logZ = logf(zsum) + lmax;
        const float lp   = sa - logZ;
        const float H    = logZ - ssum / zsum;
        const float v    = cmax * 0.5f + (csum / (float)NP) * 0.5f;
        out[g]         = (float)a;
        out[G + g]     = lp;
        out[2 * G + g] = H;
        out[3 * G + g] = v;
    }
}

extern "C" void kernel_launch(void* const* d_in, const int* in_sizes, int n_in,
                              void* d_out, int out_size, void* d_ws, size_t ws_size,
                              hipStream_t stream)
{
    const float* inputs = (const float*)d_in[0];
    const float* W_in   = (const float*)d_in[1];
    const float* b_in   = (const float*)d_in[2];
    const float* W_msg  = (const float*)d_in[3];
    const float* b_msg  = (const float*)d_in[4];
    const float* W_upd  = (const float*)d_in[5];
    const float* b_upd  = (const float*)d_in[6];
    const float* W_a1   = (const float*)d_in[7];
    const float* b_a1   = (const float*)d_in[8];
    const float* W_a2   = (const float*)d_in[9];
    const float* b_a2   = (const float*)d_in[10];
    const float* W_c1   = (const float*)d_in[11];
    const float* b_c1   = (const float*)d_in[12];
    const float* W_c2   = (const float*)d_in[13];
    const float* b_c2   = (const float*)d_in[14];
    const int* edge_src = (const int*)d_in[15];
    const int* edge_dst = (const int*)d_in[16];
    const int* actions  = (const int*)d_in[17];

    const int N  = in_sizes[0] / 128;
    const int E  = in_sizes[15];
    const int G  = in_sizes[17];
    const int NP = N / G;
    const int nbuk = (N + NPB - 1) >> NPB_SHIFT;

    float* out = (float*)d_out;                     // updates [N*128] f32 + 4G tail

    // workspace layout (bf16 activations)
    u16* in_bf  = (u16*)d_ws;                       // [N*128]
    u16* ns_bf  = in_bf  + (size_t)N * 128;         // [N*128]
    u16* msg_bf = ns_bf  + (size_t)N * 128;         // [N*128]
    u16* agg_bf = msg_bf + (size_t)N * 128;         // [N*128]
    u16* Wt_in  = agg_bf + (size_t)N * 128;         // [128*128]
    u16* Wt_msg = Wt_in  + 128 * 128;               // [128*128]
    u16* Wt_upd = Wt_msg + 128 * 128;               // [128*256]
    float* logits = (float*)(Wt_upd + 128 * 256);   // [N]
    float* crit   = logits + N;                     // [N]
    int*   offs    = (int*)(crit + N);              // [N+1]
    int*   csr     = offs + (N + 1);                // [E]
    int*   bcursor = csr + E;                       // [nbuk]
    int*   ebase   = bcursor + MAX_BUK;             // [nbuk]
    int*   ebuf    = ebase + MAX_BUK;               // [nbuk * EBUF_CAP]

    hipMemsetAsync(bcursor, 0, (size_t)nbuk * sizeof(int), stream);

    const int chunk = 4096;
    const int binGrid  = (E + chunk - 1) / chunk;
    const int gemmGrid = (N + 63) / 64;
    const long long n8 = (long long)N * 128 / 8;

    // conversions
    convert_inputs_kernel<<<(int)((n8 + 255) / 256), 256, 0, stream>>>(inputs, in_bf, n8);
    convert_w_kernel<<<16, 256, 0, stream>>>(W_in,  Wt_in,  128);
    convert_w_kernel<<<16, 256, 0, stream>>>(W_msg, Wt_msg, 128);
    convert_w_kernel<<<32, 256, 0, stream>>>(W_upd, Wt_upd, 256);
    // CSR build
    bin_edges_kernel<<<binGrid, 256, 0, stream>>>(edge_src, edge_dst, bcursor, ebuf, E, nbuk, chunk);
    scan_buckets_kernel<<<1, 1024, 0, stream>>>(bcursor, ebase, nbuk, offs, N, E);
    build_csr_kernel<<<nbuk, 256, 0, stream>>>(ebuf, bcursor, ebase, offs, csr, N);
    // node_states = relu(inputs @ W_in + b_in)  (bf16 out)
    mfma_gemm_kernel<128, false><<<gemmGrid, 256, 0, stream>>>(in_bf, nullptr, Wt_in, b_in, nullptr, ns_bf, N);
    // messages = relu(ns @ W_msg + b_msg)  (bf16 out)
    mfma_gemm_kernel<128, false><<<gemmGrid, 256, 0, stream>>>(ns_bf, nullptr, Wt_msg, b_msg, nullptr, msg_bf, N);
    // agg = segment_sum(messages) via CSR gather
    gather_bf16_kernel<<<(N + 15) / 16, 256, 0, stream>>>(offs, csr, msg_bf, agg_bf, N);
    // updates = relu([agg | ns] @ W_upd + b_upd)  (f32 out -> d_out)
    mfma_gemm_kernel<256, true><<<gemmGrid, 256, 0, stream>>>(agg_bf, ns_bf, Wt_upd, b_upd, out, nullptr, N);
    // heads
    head_kernel<<<N / 8, 256, 0, stream>>>(out, W_a1, b_a1, W_a2, b_a2, W_c1, b_c1, W_c2, b_c2, logits, crit);
    // per-graph outputs
    finalize_kernel<<<G, 1024, 0, stream>>>(logits, crit, actions, out + (size_t)N * 128, NP, G);
}

// Round 7
// 227.808 us; speedup vs baseline: 13.2587x; 1.3284x over previous
//
#include <hip/hip_runtime.h>
#include <math.h>

typedef unsigned short u16;
typedef unsigned int   u32;
typedef __attribute__((ext_vector_type(8))) short short8v;
typedef __attribute__((ext_vector_type(4))) float f32x4;

__device__ __forceinline__ u16 f2bf(float x) {
    u32 u = __float_as_uint(x);
    u += 0x7FFFu + ((u >> 16) & 1u);   // RNE
    return (u16)(u >> 16);
}
__device__ __forceinline__ float bf_lo(u32 u) { return __uint_as_float(u << 16); }
__device__ __forceinline__ float bf_hi(u32 u) { return __uint_as_float(u & 0xFFFF0000u); }

// ---------------- convert inputs f32 -> bf16 (8 elems/thread) ----------------
__global__ __launch_bounds__(256) void convert_inputs_kernel(
    const float* __restrict__ x, u16* __restrict__ y, long long n8)
{
    const long long i = (long long)blockIdx.x * 256 + threadIdx.x;
    if (i >= n8) return;
    const float4 a = ((const float4*)x)[i * 2 + 0];
    const float4 b = ((const float4*)x)[i * 2 + 1];
    u16 r[8] = {f2bf(a.x), f2bf(a.y), f2bf(a.z), f2bf(a.w),
                f2bf(b.x), f2bf(b.y), f2bf(b.z), f2bf(b.w)};
    ((uint4*)y)[i] = *(uint4*)r;
}

// ---------------- convert+transpose weight: W[K][128] f32 -> Wt[128][K] bf16 ----------------
__global__ __launch_bounds__(256) void convert_w_kernel(
    const float* __restrict__ W, u16* __restrict__ Wt, int K)
{
    for (int idx = blockIdx.x * 256 + threadIdx.x; idx < 128 * K; idx += gridDim.x * 256) {
        const int c = idx / K, k = idx - c * K;
        Wt[idx] = f2bf(W[k * 128 + c]);
    }
}

// ---------------- convert+transpose head weights -> Wh[32][128] bf16 (cols 0-15 actor, 16-31 critic) ----------------
__global__ __launch_bounds__(256) void convert_head_w_kernel(
    const float* __restrict__ Wa1, const float* __restrict__ Wc1, u16* __restrict__ Wh)
{
    const int idx = blockIdx.x * 256 + threadIdx.x;
    if (idx >= 32 * 128) return;
    const int col = idx >> 7, k = idx & 127;
    const float v = (col < 16) ? Wa1[k * 16 + col] : Wc1[k * 16 + (col - 16)];
    Wh[idx] = f2bf(v);
}

// ---------------- MFMA GEMM: C[rows][128] = relu(concat(A1,A2)[rows][K] @ W + bias) ----------------
// Wt: [128 cols][K] bf16 (pre-transposed). Output: bf16 (Cb) and/or f32 (Cf).
template<int K, bool OUT_F32>
__global__ __launch_bounds__(256) void mfma_gemm_kernel(
    const u16* __restrict__ A1, const u16* __restrict__ A2,
    const u16* __restrict__ Wt, const float* __restrict__ bias,
    float* __restrict__ Cf, u16* __restrict__ Cb, int rows)
{
    constexpr int KS  = K / 32;        // k-steps
    constexpr int LDW = K + 8;         // +8 bf16 pad: 16B-aligned rows, bank-spread
    __shared__ u16 WtL[128][LDW];

    const int tid = threadIdx.x;
    // stage Wt -> LDS (uint4 = 8 bf16)
    const int nu4 = 128 * K / 8;
    for (int i = tid; i < nu4; i += 256) {
        const int row = i / (K / 8), k8 = i - row * (K / 8);
        *(uint4*)&WtL[row][k8 * 8] = ((const uint4*)Wt)[i];
    }

    const int lane = tid & 63, wave = tid >> 6;
    const int lrow = lane & 15, lk = lane >> 4;
    const int r0   = blockIdx.x * 64 + wave * 16;
    const int arow = r0 + lrow;
    const bool rowok = arow < rows;

    // A fragments: lane holds row (lane&15), k = ks*32 + (lane>>4)*8 + {0..7}
    short8v a[KS];
#pragma unroll
    for (int ks = 0; ks < KS; ++ks) {
        const int k = ks * 32 + lk * 8;
        const u16* p = (K == 256 && k >= 128) ? (A2 + (size_t)arow * 128 + (k - 128))
                                              : (A1 + (size_t)arow * 128 + k);
        short8v av = {};
        if (rowok) av = *(const short8v*)p;
        a[ks] = av;
    }
    float bcol[8];
#pragma unroll
    for (int n = 0; n < 8; ++n) bcol[n] = bias[n * 16 + lrow];

    __syncthreads();

    f32x4 acc[8];
#pragma unroll
    for (int n = 0; n < 8; ++n) acc[n] = (f32x4){0.f, 0.f, 0.f, 0.f};

#pragma unroll
    for (int ks = 0; ks < KS; ++ks) {
#pragma unroll
        for (int n = 0; n < 8; ++n) {
            const short8v b = *(const short8v*)&WtL[n * 16 + lrow][ks * 32 + lk * 8];
            acc[n] = __builtin_amdgcn_mfma_f32_16x16x32_bf16(a[ks], b, acc[n], 0, 0, 0);
        }
    }

    // epilogue: C/D layout col = lane&15, row = 4*(lane>>4) + reg
#pragma unroll
    for (int reg = 0; reg < 4; ++reg) {
        const int row = r0 + lk * 4 + reg;
        if (row >= rows) continue;
#pragma unroll
        for (int n = 0; n < 8; ++n) {
            const float v = fmaxf(acc[n][reg] + bcol[n], 0.f);
            const size_t o = (size_t)row * 128 + n * 16 + lrow;
            if (OUT_F32) {
                Cf[o] = v;
                if (Cb) Cb[o] = f2bf(v);
            } else {
                Cb[o] = f2bf(v);
            }
        }
    }
}

// ---------------- MFMA heads: logits[N], crit[N] from bf16 updates ----------------
__global__ __launch_bounds__(256) void head_mfma_kernel(
    const u16* __restrict__ U,      // [N][128] bf16
    const u16* __restrict__ Wh,     // [32][128] bf16 (col-major heads: 0-15 actor, 16-31 critic)
    const float* __restrict__ ba1, const float* __restrict__ Wa2, const float* __restrict__ ba2,
    const float* __restrict__ bc1, const float* __restrict__ Wc2, const float* __restrict__ bc2,
    float* __restrict__ logits, float* __restrict__ crit, int N)
{
    const int tid = threadIdx.x;
    const int lane = tid & 63, wave = tid >> 6;
    const int lrow = lane & 15, lk = lane >> 4;
    const int r0 = blockIdx.x * 64 + wave * 16;
    const int arow = r0 + lrow;
    const bool rowok = arow < N;

    short8v a[4], b0[4], b1[4];
#pragma unroll
    for (int ks = 0; ks < 4; ++ks) {
        const int k = ks * 32 + lk * 8;
        short8v av = {};
        if (rowok) av = *(const short8v*)(U + (size_t)arow * 128 + k);
        a[ks]  = av;
        b0[ks] = *(const short8v*)(Wh + (size_t)lrow * 128 + k);
        b1[ks] = *(const short8v*)(Wh + (size_t)(16 + lrow) * 128 + k);
    }
    f32x4 acc0 = (f32x4){0.f, 0.f, 0.f, 0.f};
    f32x4 acc1 = (f32x4){0.f, 0.f, 0.f, 0.f};
#pragma unroll
    for (int ks = 0; ks < 4; ++ks) {
        acc0 = __builtin_amdgcn_mfma_f32_16x16x32_bf16(a[ks], b0[ks], acc0, 0, 0, 0);
        acc1 = __builtin_amdgcn_mfma_f32_16x16x32_bf16(a[ks], b1[ks], acc1, 0, 0, 0);
    }
    const float wa = Wa2[lrow], wc = Wc2[lrow];
    const float ha = ba1[lrow], hc = bc1[lrow];
    const float b2a = ba2[0],   b2c = bc2[0];
#pragma unroll
    for (int reg = 0; reg < 4; ++reg) {
        float pa = fmaxf(acc0[reg] + ha, 0.f) * wa;
        float pc = fmaxf(acc1[reg] + hc, 0.f) * wc;
#pragma unroll
        for (int off = 8; off >= 1; off >>= 1) {
            pa += __shfl_xor(pa, off);
            pc += __shfl_xor(pc, off);
        }
        const int row = r0 + lk * 4 + reg;
        if (lrow == 0 && row < N) {
            logits[row] = pa + b2a;
            crit[row]   = pc + b2c;
        }
    }
}

// ---------------- CSR build via two-pass LDS-binned counting sort ----------------
#define NPB        256
#define NPB_SHIFT  8
#define EBUF_CAP   4608
#define MAX_BUK    512

__global__ __launch_bounds__(256) void bin_edges_kernel(
    const int* __restrict__ src, const int* __restrict__ dst,
    int* __restrict__ bcursor, int* __restrict__ ebuf,
    int E, int nbuk, int chunk)
{
    __shared__ int lcount[MAX_BUK];
    __shared__ int lbase[MAX_BUK];
    const int tid = threadIdx.x;
    const int e0 = blockIdx.x * chunk;
    const int e1 = min(e0 + chunk, E);
    for (int b = tid; b < nbuk; b += 256) lcount[b] = 0;
    __syncthreads();
    for (int i = e0 + tid; i < e1; i += 256)
        atomicAdd(&lcount[dst[i] >> NPB_SHIFT], 1);
    __syncthreads();
    for (int b = tid; b < nbuk; b += 256) {
        const int c = lcount[b];
        lbase[b] = c ? atomicAdd(&bcursor[b], c) : 0;
        lcount[b] = 0;
    }
    __syncthreads();
    for (int i = e0 + tid; i < e1; i += 256) {
        const int d = dst[i];
        const int b = d >> NPB_SHIFT;
        const int p = lbase[b] + atomicAdd(&lcount[b], 1);
        ebuf[b * EBUF_CAP + min(p, EBUF_CAP - 1)] = (src[i] << NPB_SHIFT) | (d & (NPB - 1));
    }
}

__global__ __launch_bounds__(1024) void scan_buckets_kernel(
    const int* __restrict__ bcursor, int* __restrict__ ebase,
    int nbuk, int* __restrict__ offs, int N, int E)
{
    __shared__ int ws[16], wp[16];
    const int t = threadIdx.x;
    const int v = (t < nbuk) ? bcursor[t] : 0;
    const int lane = t & 63, wid = t >> 6;
    int x = v;
#pragma unroll
    for (int off = 1; off < 64; off <<= 1) {
        const int y = __shfl_up(x, off);
        if (lane >= off) x += y;
    }
    if (lane == 63) ws[wid] = x;
    __syncthreads();
    if (t == 0) { int s = 0; for (int w = 0; w < 16; ++w) { wp[w] = s; s += ws[w]; } }
    __syncthreads();
    if (t < nbuk) ebase[t] = x - v + wp[wid];
    if (t == 0) offs[N] = E;
}

__global__ __launch_bounds__(256) void build_csr_kernel(
    const int* __restrict__ ebuf, const int* __restrict__ bcursor,
    const int* __restrict__ ebase,
    int* __restrict__ offs, int* __restrict__ csr, int N)
{
    __shared__ int ndeg[NPB];
    __shared__ int nofs[NPB];
    __shared__ int ws[4], wp[4];
    const int b   = blockIdx.x;
    const int tid = threadIdx.x;
    const int cnt  = min(bcursor[b], EBUF_CAP);
    const int base = ebase[b];
    const int* eb = ebuf + b * EBUF_CAP;

    ndeg[tid] = 0;
    __syncthreads();
    for (int j = tid; j < cnt; j += 256)
        atomicAdd(&ndeg[eb[j] & (NPB - 1)], 1);
    __syncthreads();

    const int lane = tid & 63, wid = tid >> 6;
    const int v = ndeg[tid];
    int x = v;
#pragma unroll
    for (int off = 1; off < 64; off <<= 1) {
        const int y = __shfl_up(x, off);
        if (lane >= off) x += y;
    }
    if (lane == 63) ws[wid] = x;
    __syncthreads();
    if (tid == 0) { int s = 0; for (int w = 0; w < 4; ++w) { wp[w] = s; s += ws[w]; } }
    __syncthreads();
    const int excl = x - v + wp[wid];
    nofs[tid] = excl;
    const int node = (b << NPB_SHIFT) + tid;
    if (node < N) offs[node] = base + excl;
    ndeg[tid] = 0;
    __syncthreads();

    for (int j = tid; j < cnt; j += 256) {
        const int e = eb[j];
        const int d = e & (NPB - 1);
        const int p = atomicAdd(&ndeg[d], 1);
        csr[base + nofs[d] + p] = e >> NPB_SHIFT;
    }
}

// ---------------- gather (bf16): agg[n] = sum over in-edges of msg[src] ----------------
__global__ __launch_bounds__(256) void gather_bf16_kernel(
    const int* __restrict__ offs, const int* __restrict__ csr,
    const u16* __restrict__ msg, u16* __restrict__ agg, int N)
{
    const int node = blockIdx.x * 16 + (threadIdx.x >> 4);
    if (node >= N) return;
    const int c8 = threadIdx.x & 15;      // which 16B (8 bf16) chunk of the 128-wide row
    int j = offs[node];
    const int j1 = offs[node + 1];
    const uint4* mv = (const uint4*)msg;
    float acc[8] = {0.f, 0.f, 0.f, 0.f, 0.f, 0.f, 0.f, 0.f};
    for (; j + 1 < j1; j += 2) {
        const int s0 = csr[j], s1 = csr[j + 1];
        const uint4 u = mv[(size_t)s0 * 16 + c8];
        const uint4 v = mv[(size_t)s1 * 16 + c8];
        acc[0] += bf_lo(u.x); acc[1] += bf_hi(u.x);
        acc[2] += bf_lo(u.y); acc[3] += bf_hi(u.y);
        acc[4] += bf_lo(u.z); acc[5] += bf_hi(u.z);
        acc[6] += bf_lo(u.w); acc[7] += bf_hi(u.w);
        acc[0] += bf_lo(v.x); acc[1] += bf_hi(v.x);
        acc[2] += bf_lo(v.y); acc[3] += bf_hi(v.y);
        acc[4] += bf_lo(v.z); acc[5] += bf_hi(v.z);
        acc[6] += bf_lo(v.w); acc[7] += bf_hi(v.w);
    }
    if (j < j1) {
        const uint4 u = mv[(size_t)csr[j] * 16 + c8];
        acc[0] += bf_lo(u.x); acc[1] += bf_hi(u.x);
        acc[2] += bf_lo(u.y); acc[3] += bf_hi(u.y);
        acc[4] += bf_lo(u.z); acc[5] += bf_hi(u.z);
        acc[6] += bf_lo(u.w); acc[7] += bf_hi(u.w);
    }
    u16 r[8];
#pragma unroll
    for (int q = 0; q < 8; ++q) r[q] = f2bf(acc[q]);
    ((uint4*)agg)[(size_t)node * 16 + c8] = *(uint4*)r;
}

// ---------------- per-graph finalize ----------------
__device__ __forceinline__ float blockRedMax(float v, float* red) {
#pragma unroll
    for (int o = 32; o >= 1; o >>= 1) v = fmaxf(v, __shfl_xor(v, o));
    const int w = threadIdx.x >> 6;
    __syncthreads();
    if ((threadIdx.x & 63) == 0) red[w] = v;
    __syncthreads();
    if (threadIdx.x < 16) {
        float x = red[threadIdx.x];
#pragma unroll
        for (int o = 8; o >= 1; o >>= 1) x = fmaxf(x, __shfl_xor(x, o));
        if (threadIdx.x == 0) red[0] = x;
    }
    __syncthreads();
    const float r = red[0];
    __syncthreads();
    return r;
}

__device__ __forceinline__ float blockRedSum(float v, float* red) {
#pragma unroll
    for (int o = 32; o >= 1; o >>= 1) v += __shfl_xor(v, o);
    const int w = threadIdx.x >> 6;
    __syncthreads();
    if ((threadIdx.x & 63) == 0) red[w] = v;
    __syncthreads();
    if (threadIdx.x < 16) {
        float x = red[threadIdx.x];
#pragma unroll
        for (int o = 8; o >= 1; o >>= 1) x += __shfl_xor(x, o);
        if (threadIdx.x == 0) red[0] = x;
    }
    __syncthreads();
    const float r = red[0];
    __syncthreads();
    return r;
}

__global__ __launch_bounds__(1024) void finalize_kernel(
    const float* __restrict__ logits, const float* __restrict__ crit,
    const int* __restrict__ actions, float* __restrict__ out, int NP, int G)
{
    __shared__ float slog[12512];
    __shared__ float red[16];
    const int g = blockIdx.x;
    const int tid = threadIdx.x;
    const float* lg = logits + (long long)g * NP;
    const float* cg = crit   + (long long)g * NP;

    float lmax = -3.402823466e38f, cmax = -3.402823466e38f, csum = 0.f;
    for (int i = tid; i < NP; i += 1024) {
        const float l = lg[i], c = cg[i];
        slog[i] = l;
        lmax = fmaxf(lmax, l);
        cmax = fmaxf(cmax, c);
        csum += c;
    }
    __syncthreads();
    lmax = blockRedMax(lmax, red);
    cmax = blockRedMax(cmax, red);
    csum = blockRedSum(csum, red);

    float zsum = 0.f, ssum = 0.f;
    for (int i = tid; i < NP; i += 1024) {
        const float s = slog[i];
        const float e = expf(s - lmax);
        zsum += e;
        ssum += s * e;
    }
    zsum = blockRedSum(zsum, red);
    ssum = blockRedSum(ssum, red);

    if (tid == 0) {
        const int a = actions[g];
        const float sa   = slog[a];
        const float logZ = logf(zsum) + lmax;
        const float lp   = sa - logZ;
        const float H    = logZ - ssum / zsum;
        const float v    = cmax * 0.5f + (csum / (float)NP) * 0.5f;
        out[g]         = (float)a;
        out[G + g]     = lp;
        out[2 * G + g] = H;
        out[3 * G + g] = v;
    }
}

extern "C" void kernel_launch(void* const* d_in, const int* in_sizes, int n_in,
                              void* d_out, int out_size, void* d_ws, size_t ws_size,
                              hipStream_t stream)
{
    const float* inputs = (const float*)d_in[0];
    const float* W_in   = (const float*)d_in[1];
    const float* b_in   = (const float*)d_in[2];
    const float* W_msg  = (const float*)d_in[3];
    const float* b_msg  = (const float*)d_in[4];
    const float* W_upd  = (const float*)d_in[5];
    const float* b_upd  = (const float*)d_in[6];
    const float* W_a1   = (const float*)d_in[7];
    const float* b_a1   = (const float*)d_in[8];
    const float* W_a2   = (const float*)d_in[9];
    const float* b_a2   = (const float*)d_in[10];
    const float* W_c1   = (const float*)d_in[11];
    const float* b_c1   = (const float*)d_in[12];
    const float* W_c2   = (const float*)d_in[13];
    const float* b_c2   = (const float*)d_in[14];
    const int* edge_src = (const int*)d_in[15];
    const int* edge_dst = (const int*)d_in[16];
    const int* actions  = (const int*)d_in[17];

    const int N  = in_sizes[0] / 128;
    const int E  = in_sizes[15];
    const int G  = in_sizes[17];
    const int NP = N / G;
    const int nbuk = (N + NPB - 1) >> NPB_SHIFT;

    float* out = (float*)d_out;                     // updates [N*128] f32 + 4G tail

    // workspace layout (bf16 activations)
    u16* in_bf  = (u16*)d_ws;                       // [N*128]  (reused as u_bf after GEMM1)
    u16* ns_bf  = in_bf  + (size_t)N * 128;         // [N*128]
    u16* msg_bf = ns_bf  + (size_t)N * 128;         // [N*128]
    u16* agg_bf = msg_bf + (size_t)N * 128;         // [N*128]
    u16* Wt_in  = agg_bf + (size_t)N * 128;         // [128*128]
    u16* Wt_msg = Wt_in  + 128 * 128;               // [128*128]
    u16* Wt_upd = Wt_msg + 128 * 128;               // [128*256]
    u16* Wh     = Wt_upd + 128 * 256;               // [32*128] head weights
    float* logits = (float*)(Wh + 32 * 128);        // [N]
    float* crit   = logits + N;                     // [N]
    int*   offs    = (int*)(crit + N);              // [N+1]
    int*   csr     = offs + (N + 1);                // [E]
    int*   bcursor = csr + E;                       // [nbuk]
    int*   ebase   = bcursor + MAX_BUK;             // [nbuk]
    int*   ebuf    = ebase + MAX_BUK;               // [nbuk * EBUF_CAP]

    u16* u_bf = in_bf;   // bf16 copy of updates (in_bf is dead after GEMM1)

    hipMemsetAsync(bcursor, 0, (size_t)nbuk * sizeof(int), stream);

    const int chunk = 4096;
    const int binGrid  = (E + chunk - 1) / chunk;
    const int gemmGrid = (N + 63) / 64;
    const long long n8 = (long long)N * 128 / 8;

    // conversions
    convert_inputs_kernel<<<(int)((n8 + 255) / 256), 256, 0, stream>>>(inputs, in_bf, n8);
    convert_w_kernel<<<16, 256, 0, stream>>>(W_in,  Wt_in,  128);
    convert_w_kernel<<<16, 256, 0, stream>>>(W_msg, Wt_msg, 128);
    convert_w_kernel<<<32, 256, 0, stream>>>(W_upd, Wt_upd, 256);
    convert_head_w_kernel<<<16, 256, 0, stream>>>(W_a1, W_c1, Wh);
    // CSR build
    bin_edges_kernel<<<binGrid, 256, 0, stream>>>(edge_src, edge_dst, bcursor, ebuf, E, nbuk, chunk);
    scan_buckets_kernel<<<1, 1024, 0, stream>>>(bcursor, ebase, nbuk, offs, N, E);
    build_csr_kernel<<<nbuk, 256, 0, stream>>>(ebuf, bcursor, ebase, offs, csr, N);
    // node_states = relu(inputs @ W_in + b_in)  (bf16 out)
    mfma_gemm_kernel<128, false><<<gemmGrid, 256, 0, stream>>>(in_bf, nullptr, Wt_in, b_in, nullptr, ns_bf, N);
    // messages = relu(ns @ W_msg + b_msg)  (bf16 out)
    mfma_gemm_kernel<128, false><<<gemmGrid, 256, 0, stream>>>(ns_bf, nullptr, Wt_msg, b_msg, nullptr, msg_bf, N);
    // agg = segment_sum(messages) via CSR gather
    gather_bf16_kernel<<<(N + 15) / 16, 256, 0, stream>>>(offs, csr, msg_bf, agg_bf, N);
    // updates = relu([agg | ns] @ W_upd + b_upd)  (f32 -> d_out, bf16 -> u_bf)
    mfma_gemm_kernel<256, true><<<gemmGrid, 256, 0, stream>>>(agg_bf, ns_bf, Wt_upd, b_upd, out, u_bf, N);
    // heads (MFMA over bf16 updates)
    head_mfma_kernel<<<gemmGrid, 256, 0, stream>>>(u_bf, Wh, b_a1, W_a2, b_a2, b_c1, W_c2, b_c2, logits, crit, N);
    // per-graph outputs
    finalize_kernel<<<G, 1024, 0, stream>>>(logits, crit, actions, out + (size_t)N * 128, NP, G);
}

// Round 8
// 203.319 us; speedup vs baseline: 14.8556x; 1.1204x over previous
//
#include <hip/hip_runtime.h>
#include <math.h>

typedef unsigned short u16;
typedef unsigned int   u32;
typedef __attribute__((ext_vector_type(8))) short short8v;
typedef __attribute__((ext_vector_type(4))) float f32x4;

__device__ __forceinline__ u16 f2bf(float x) {
    u32 u = __float_as_uint(x);
    u += 0x7FFFu + ((u >> 16) & 1u);   // RNE
    return (u16)(u >> 16);
}
__device__ __forceinline__ float bf_lo(u32 u) { return __uint_as_float(u << 16); }
__device__ __forceinline__ float bf_hi(u32 u) { return __uint_as_float(u & 0xFFFF0000u); }

// ---------------- all weight conversions in one kernel ----------------
// Wt_in[128][128], Wt_msg[128][128], Wt_upd[128][256] (transposed), Wh[32][128]
__global__ __launch_bounds__(256) void convert_weights_kernel(
    const float* __restrict__ W_in, const float* __restrict__ W_msg,
    const float* __restrict__ W_upd,
    const float* __restrict__ Wa1, const float* __restrict__ Wc1,
    u16* __restrict__ Wt_in, u16* __restrict__ Wt_msg,
    u16* __restrict__ Wt_upd, u16* __restrict__ Wh)
{
    const int idx = blockIdx.x * 256 + threadIdx.x;
    if (idx < 16384) {                       // Wt_in
        const int c = idx >> 7, k = idx & 127;
        Wt_in[c * 128 + k] = f2bf(W_in[k * 128 + c]);
    } else if (idx < 32768) {                // Wt_msg
        const int i = idx - 16384;
        const int c = i >> 7, k = i & 127;
        Wt_msg[c * 128 + k] = f2bf(W_msg[k * 128 + c]);
    } else if (idx < 65536) {                // Wt_upd
        const int i = idx - 32768;
        const int c = i >> 8, k = i & 255;
        Wt_upd[c * 256 + k] = f2bf(W_upd[k * 128 + c]);
    } else if (idx < 65536 + 4096) {         // Wh
        const int i = idx - 65536;
        const int col = i >> 7, k = i & 127;
        const float v = (col < 16) ? Wa1[k * 16 + col] : Wc1[k * 16 + (col - 16)];
        Wh[col * 128 + k] = f2bf(v);
    }
}

// ---------------- MFMA GEMM: C[rows][128] = relu(concat(A1,A2)[rows][K] @ W + bias) ----------------
// A_F32: A1f is f32 (converted to bf16 in fragment load); else A1/A2 bf16.
// Wt: [128 cols][K] bf16 (pre-transposed). Output: f32 (Cf) or bf16 (Cb).
template<int K, bool OUT_F32, bool A_F32>
__global__ __launch_bounds__(256) void mfma_gemm_kernel(
    const u16* __restrict__ A1, const u16* __restrict__ A2,
    const float* __restrict__ A1f,
    const u16* __restrict__ Wt, const float* __restrict__ bias,
    float* __restrict__ Cf, u16* __restrict__ Cb, int rows)
{
    constexpr int KS  = K / 32;        // k-steps
    constexpr int LDW = K + 8;         // +8 bf16 pad: 16B-aligned rows, bank-spread
    __shared__ u16 WtL[128][LDW];

    const int tid = threadIdx.x;
    const int nu4 = 128 * K / 8;
    for (int i = tid; i < nu4; i += 256) {
        const int row = i / (K / 8), k8 = i - row * (K / 8);
        *(uint4*)&WtL[row][k8 * 8] = ((const uint4*)Wt)[i];
    }

    const int lane = tid & 63, wave = tid >> 6;
    const int lrow = lane & 15, lk = lane >> 4;
    const int r0   = blockIdx.x * 64 + wave * 16;
    const int arow = r0 + lrow;
    const bool rowok = arow < rows;

    short8v a[KS];
#pragma unroll
    for (int ks = 0; ks < KS; ++ks) {
        const int k = ks * 32 + lk * 8;
        short8v av = {};
        if (rowok) {
            if (A_F32) {
                const float* pf = A1f + (size_t)arow * 128 + k;
                const float4 x0 = *(const float4*)pf;
                const float4 x1 = *(const float4*)(pf + 4);
                u16 t[8] = {f2bf(x0.x), f2bf(x0.y), f2bf(x0.z), f2bf(x0.w),
                            f2bf(x1.x), f2bf(x1.y), f2bf(x1.z), f2bf(x1.w)};
                av = *(short8v*)t;
            } else {
                const u16* p = (K == 256 && k >= 128) ? (A2 + (size_t)arow * 128 + (k - 128))
                                                      : (A1 + (size_t)arow * 128 + k);
                av = *(const short8v*)p;
            }
        }
        a[ks] = av;
    }
    float bcol[8];
#pragma unroll
    for (int n = 0; n < 8; ++n) bcol[n] = bias[n * 16 + lrow];

    __syncthreads();

    f32x4 acc[8];
#pragma unroll
    for (int n = 0; n < 8; ++n) acc[n] = (f32x4){0.f, 0.f, 0.f, 0.f};

#pragma unroll
    for (int ks = 0; ks < KS; ++ks) {
#pragma unroll
        for (int n = 0; n < 8; ++n) {
            const short8v b = *(const short8v*)&WtL[n * 16 + lrow][ks * 32 + lk * 8];
            acc[n] = __builtin_amdgcn_mfma_f32_16x16x32_bf16(a[ks], b, acc[n], 0, 0, 0);
        }
    }

    // epilogue: C/D layout col = lane&15, row = 4*(lane>>4) + reg
#pragma unroll
    for (int reg = 0; reg < 4; ++reg) {
        const int row = r0 + lk * 4 + reg;
        if (row >= rows) continue;
#pragma unroll
        for (int n = 0; n < 8; ++n) {
            const float v = fmaxf(acc[n][reg] + bcol[n], 0.f);
            const size_t o = (size_t)row * 128 + n * 16 + lrow;
            if (OUT_F32) Cf[o] = v;
            else         Cb[o] = f2bf(v);
        }
    }
}

// ---------------- MFMA heads from f32 updates: logits[N], crit[N] ----------------
__global__ __launch_bounds__(256) void head_mfma_kernel(
    const float* __restrict__ U,    // [N][128] f32
    const u16* __restrict__ Wh,     // [32][128] bf16 (cols 0-15 actor, 16-31 critic)
    const float* __restrict__ ba1, const float* __restrict__ Wa2, const float* __restrict__ ba2,
    const float* __restrict__ bc1, const float* __restrict__ Wc2, const float* __restrict__ bc2,
    float* __restrict__ logits, float* __restrict__ crit, int N)
{
    const int tid = threadIdx.x;
    const int lane = tid & 63, wave = tid >> 6;
    const int lrow = lane & 15, lk = lane >> 4;
    const int r0 = blockIdx.x * 64 + wave * 16;
    const int arow = r0 + lrow;
    const bool rowok = arow < N;

    short8v a[4], b0[4], b1[4];
#pragma unroll
    for (int ks = 0; ks < 4; ++ks) {
        const int k = ks * 32 + lk * 8;
        short8v av = {};
        if (rowok) {
            const float* pf = U + (size_t)arow * 128 + k;
            const float4 x0 = *(const float4*)pf;
            const float4 x1 = *(const float4*)(pf + 4);
            u16 t[8] = {f2bf(x0.x), f2bf(x0.y), f2bf(x0.z), f2bf(x0.w),
                        f2bf(x1.x), f2bf(x1.y), f2bf(x1.z), f2bf(x1.w)};
            av = *(short8v*)t;
        }
        a[ks]  = av;
        b0[ks] = *(const short8v*)(Wh + (size_t)lrow * 128 + k);
        b1[ks] = *(const short8v*)(Wh + (size_t)(16 + lrow) * 128 + k);
    }
    f32x4 acc0 = (f32x4){0.f, 0.f, 0.f, 0.f};
    f32x4 acc1 = (f32x4){0.f, 0.f, 0.f, 0.f};
#pragma unroll
    for (int ks = 0; ks < 4; ++ks) {
        acc0 = __builtin_amdgcn_mfma_f32_16x16x32_bf16(a[ks], b0[ks], acc0, 0, 0, 0);
        acc1 = __builtin_amdgcn_mfma_f32_16x16x32_bf16(a[ks], b1[ks], acc1, 0, 0, 0);
    }
    const float wa = Wa2[lrow], wc = Wc2[lrow];
    const float ha = ba1[lrow], hc = bc1[lrow];
    const float b2a = ba2[0],   b2c = bc2[0];
#pragma unroll
    for (int reg = 0; reg < 4; ++reg) {
        float pa = fmaxf(acc0[reg] + ha, 0.f) * wa;
        float pc = fmaxf(acc1[reg] + hc, 0.f) * wc;
#pragma unroll
        for (int off = 8; off >= 1; off >>= 1) {
            pa += __shfl_xor(pa, off);
            pc += __shfl_xor(pc, off);
        }
        const int row = r0 + lk * 4 + reg;
        if (lrow == 0 && row < N) {
            logits[row] = pa + b2a;
            crit[row]   = pc + b2c;
        }
    }
}

// ---------------- CSR build via two-pass LDS-binned counting sort ----------------
#define NPB        256
#define NPB_SHIFT  8
#define EBUF_CAP   4608
#define MAX_BUK    512

__global__ __launch_bounds__(256) void bin_edges_kernel(
    const int* __restrict__ src, const int* __restrict__ dst,
    int* __restrict__ bcursor, int* __restrict__ ebuf,
    int E, int nbuk, int chunk)
{
    __shared__ int lcount[MAX_BUK];
    __shared__ int lbase[MAX_BUK];
    const int tid = threadIdx.x;
    const int e0 = blockIdx.x * chunk;
    const int e1 = min(e0 + chunk, E);
    for (int b = tid; b < nbuk; b += 256) lcount[b] = 0;
    __syncthreads();
    for (int i = e0 + tid; i < e1; i += 256)
        atomicAdd(&lcount[dst[i] >> NPB_SHIFT], 1);
    __syncthreads();
    for (int b = tid; b < nbuk; b += 256) {
        const int c = lcount[b];
        lbase[b] = c ? atomicAdd(&bcursor[b], c) : 0;
        lcount[b] = 0;
    }
    __syncthreads();
    for (int i = e0 + tid; i < e1; i += 256) {
        const int d = dst[i];
        const int b = d >> NPB_SHIFT;
        const int p = lbase[b] + atomicAdd(&lcount[b], 1);
        ebuf[b * EBUF_CAP + min(p, EBUF_CAP - 1)] = (src[i] << NPB_SHIFT) | (d & (NPB - 1));
    }
}

// one block per bucket: inline bucket-prefix + LDS histogram + scan + scatter
__global__ __launch_bounds__(256) void build_csr_kernel(
    const int* __restrict__ ebuf, const int* __restrict__ bcursor,
    int* __restrict__ offs, int* __restrict__ csr, int N, int E, int nbuk)
{
    __shared__ int red[4];
    __shared__ int ndeg[NPB];
    __shared__ int nofs[NPB];
    __shared__ int ws[4], wp[4];
    const int b   = blockIdx.x;
    const int tid = threadIdx.x;

    // base = sum of bucket counts before b
    int part = 0;
    for (int i = tid; i < b; i += 256) part += bcursor[i];
#pragma unroll
    for (int off = 32; off >= 1; off >>= 1) part += __shfl_xor(part, off);
    if ((tid & 63) == 0) red[tid >> 6] = part;
    __syncthreads();
    const int base = red[0] + red[1] + red[2] + red[3];

    const int cnt = min(bcursor[b], EBUF_CAP);
    const int* eb = ebuf + b * EBUF_CAP;

    ndeg[tid] = 0;
    __syncthreads();
    for (int j = tid; j < cnt; j += 256)
        atomicAdd(&ndeg[eb[j] & (NPB - 1)], 1);
    __syncthreads();

    const int lane = tid & 63, wid = tid >> 6;
    const int v = ndeg[tid];
    int x = v;
#pragma unroll
    for (int off = 1; off < 64; off <<= 1) {
        const int y = __shfl_up(x, off);
        if (lane >= off) x += y;
    }
    if (lane == 63) ws[wid] = x;
    __syncthreads();
    if (tid == 0) { int s = 0; for (int w = 0; w < 4; ++w) { wp[w] = s; s += ws[w]; } }
    __syncthreads();
    const int excl = x - v + wp[wid];
    nofs[tid] = excl;
    const int node = (b << NPB_SHIFT) + tid;
    if (node < N) offs[node] = base + excl;
    if (b == 0 && tid == 0) offs[N] = E;
    ndeg[tid] = 0;
    __syncthreads();

    for (int j = tid; j < cnt; j += 256) {
        const int e = eb[j];
        const int d = e & (NPB - 1);
        const int p = atomicAdd(&ndeg[d], 1);
        csr[base + nofs[d] + p] = e >> NPB_SHIFT;
    }
}

// ---------------- gather (bf16, unroll-4): agg[n] = sum over in-edges of msg[src] ----------------
__device__ __forceinline__ void acc_row(float* acc, const uint4 u) {
    acc[0] += bf_lo(u.x); acc[1] += bf_hi(u.x);
    acc[2] += bf_lo(u.y); acc[3] += bf_hi(u.y);
    acc[4] += bf_lo(u.z); acc[5] += bf_hi(u.z);
    acc[6] += bf_lo(u.w); acc[7] += bf_hi(u.w);
}

__global__ __launch_bounds__(256) void gather_bf16_kernel(
    const int* __restrict__ offs, const int* __restrict__ csr,
    const u16* __restrict__ msg, u16* __restrict__ agg, int N)
{
    const int node = blockIdx.x * 16 + (threadIdx.x >> 4);
    if (node >= N) return;
    const int c8 = threadIdx.x & 15;
    int j = offs[node];
    const int j1 = offs[node + 1];
    const uint4* mv = (const uint4*)msg;
    float acc[8] = {0.f, 0.f, 0.f, 0.f, 0.f, 0.f, 0.f, 0.f};
    for (; j + 3 < j1; j += 4) {
        const int s0 = csr[j], s1 = csr[j + 1], s2 = csr[j + 2], s3 = csr[j + 3];
        const uint4 u0 = mv[(size_t)s0 * 16 + c8];
        const uint4 u1 = mv[(size_t)s1 * 16 + c8];
        const uint4 u2 = mv[(size_t)s2 * 16 + c8];
        const uint4 u3 = mv[(size_t)s3 * 16 + c8];
        acc_row(acc, u0); acc_row(acc, u1); acc_row(acc, u2); acc_row(acc, u3);
    }
    for (; j < j1; ++j) {
        const uint4 u = mv[(size_t)csr[j] * 16 + c8];
        acc_row(acc, u);
    }
    u16 r[8];
#pragma unroll
    for (int q = 0; q < 8; ++q) r[q] = f2bf(acc[q]);
    ((uint4*)agg)[(size_t)node * 16 + c8] = *(uint4*)r;
}

// ---------------- per-graph finalize ----------------
__device__ __forceinline__ float blockRedMax(float v, float* red) {
#pragma unroll
    for (int o = 32; o >= 1; o >>= 1) v = fmaxf(v, __shfl_xor(v, o));
    const int w = threadIdx.x >> 6;
    __syncthreads();
    if ((threadIdx.x & 63) == 0) red[w] = v;
    __syncthreads();
    if (threadIdx.x < 16) {
        float x = red[threadIdx.x];
#pragma unroll
        for (int o = 8; o >= 1; o >>= 1) x = fmaxf(x, __shfl_xor(x, o));
        if (threadIdx.x == 0) red[0] = x;
    }
    __syncthreads();
    const float r = red[0];
    __syncthreads();
    return r;
}

__device__ __forceinline__ float blockRedSum(float v, float* red) {
#pragma unroll
    for (int o = 32; o >= 1; o >>= 1) v += __shfl_xor(v, o);
    const int w = threadIdx.x >> 6;
    __syncthreads();
    if ((threadIdx.x & 63) == 0) red[w] = v;
    __syncthreads();
    if (threadIdx.x < 16) {
        float x = red[threadIdx.x];
#pragma unroll
        for (int o = 8; o >= 1; o >>= 1) x += __shfl_xor(x, o);
        if (threadIdx.x == 0) red[0] = x;
    }
    __syncthreads();
    const float r = red[0];
    __syncthreads();
    return r;
}

__global__ __launch_bounds__(1024) void finalize_kernel(
    const float* __restrict__ logits, const float* __restrict__ crit,
    const int* __restrict__ actions, float* __restrict__ out, int NP, int G)
{
    __shared__ float slog[12512];
    __shared__ float red[16];
    const int g = blockIdx.x;
    const int tid = threadIdx.x;
    const float* lg = logits + (long long)g * NP;
    const float* cg = crit   + (long long)g * NP;

    float lmax = -3.402823466e38f, cmax = -3.402823466e38f, csum = 0.f;
    for (int i = tid; i < NP; i += 1024) {
        const float l = lg[i], c = cg[i];
        slog[i] = l;
        lmax = fmaxf(lmax, l);
        cmax = fmaxf(cmax, c);
        csum += c;
    }
    __syncthreads();
    lmax = blockRedMax(lmax, red);
    cmax = blockRedMax(cmax, red);
    csum = blockRedSum(csum, red);

    float zsum = 0.f, ssum = 0.f;
    for (int i = tid; i < NP; i += 1024) {
        const float s = slog[i];
        const float e = expf(s - lmax);
        zsum += e;
        ssum += s * e;
    }
    zsum = blockRedSum(zsum, red);
    ssum = blockRedSum(ssum, red);

    if (tid == 0) {
        const int a = actions[g];
        const float sa   = slog[a];
        const float logZ = logf(zsum) + lmax;
        const float lp   = sa - logZ;
        const float H    = logZ - ssum / zsum;
        const float v    = cmax * 0.5f + (csum / (float)NP) * 0.5f;
        out[g]         = (float)a;
        out[G + g]     = lp;
        out[2 * G + g] = H;
        out[3 * G + g] = v;
    }
}

extern "C" void kernel_launch(void* const* d_in, const int* in_sizes, int n_in,
                              void* d_out, int out_size, void* d_ws, size_t ws_size,
                              hipStream_t stream)
{
    const float* inputs = (const float*)d_in[0];
    const float* W_in   = (const float*)d_in[1];
    const float* b_in   = (const float*)d_in[2];
    const float* W_msg  = (const float*)d_in[3];
    const float* b_msg  = (const float*)d_in[4];
    const float* W_upd  = (const float*)d_in[5];
    const float* b_upd  = (const float*)d_in[6];
    const float* W_a1   = (const float*)d_in[7];
    const float* b_a1   = (const float*)d_in[8];
    const float* W_a2   = (const float*)d_in[9];
    const float* b_a2   = (const float*)d_in[10];
    const float* W_c1   = (const float*)d_in[11];
    const float* b_c1   = (const float*)d_in[12];
    const float* W_c2   = (const float*)d_in[13];
    const float* b_c2   = (const float*)d_in[14];
    const int* edge_src = (const int*)d_in[15];
    const int* edge_dst = (const int*)d_in[16];
    const int* actions  = (const int*)d_in[17];

    const int N  = in_sizes[0] / 128;
    const int E  = in_sizes[15];
    const int G  = in_sizes[17];
    const int NP = N / G;
    const int nbuk = (N + NPB - 1) >> NPB_SHIFT;

    float* out = (float*)d_out;                     // updates [N*128] f32 + 4G tail

    // workspace layout
    u16* ns_bf  = (u16*)d_ws;                       // [N*128]
    u16* msg_bf = ns_bf  + (size_t)N * 128;         // [N*128]
    u16* agg_bf = msg_bf + (size_t)N * 128;         // [N*128]
    u16* Wt_in  = agg_bf + (size_t)N * 128;         // [128*128]
    u16* Wt_msg = Wt_in  + 128 * 128;               // [128*128]
    u16* Wt_upd = Wt_msg + 128 * 128;               // [128*256]
    u16* Wh     = Wt_upd + 128 * 256;               // [32*128]
    float* logits = (float*)(Wh + 32 * 128);        // [N]
    float* crit   = logits + N;                     // [N]
    int*   offs    = (int*)(crit + N);              // [N+1]
    int*   csr     = offs + (N + 1);                // [E]
    int*   bcursor = csr + E;                       // [nbuk]
    int*   ebuf    = bcursor + MAX_BUK;             // [nbuk * EBUF_CAP]

    hipMemsetAsync(bcursor, 0, (size_t)nbuk * sizeof(int), stream);

    const int chunk = 4096;
    const int binGrid  = (E + chunk - 1) / chunk;
    const int gemmGrid = (N + 63) / 64;

    // all weight conversions (one launch)
    convert_weights_kernel<<<(65536 + 4096 + 255) / 256, 256, 0, stream>>>(
        W_in, W_msg, W_upd, W_a1, W_c1, Wt_in, Wt_msg, Wt_upd, Wh);
    // CSR build
    bin_edges_kernel<<<binGrid, 256, 0, stream>>>(edge_src, edge_dst, bcursor, ebuf, E, nbuk, chunk);
    build_csr_kernel<<<nbuk, 256, 0, stream>>>(ebuf, bcursor, offs, csr, N, E, nbuk);
    // node_states = relu(inputs @ W_in + b_in)  (f32 in, bf16 out; conversion fused)
    mfma_gemm_kernel<128, false, true><<<gemmGrid, 256, 0, stream>>>(
        nullptr, nullptr, inputs, Wt_in, b_in, nullptr, ns_bf, N);
    // messages = relu(ns @ W_msg + b_msg)  (bf16 out)
    mfma_gemm_kernel<128, false, false><<<gemmGrid, 256, 0, stream>>>(
        ns_bf, nullptr, nullptr, Wt_msg, b_msg, nullptr, msg_bf, N);
    // agg = segment_sum(messages) via CSR gather
    gather_bf16_kernel<<<(N + 15) / 16, 256, 0, stream>>>(offs, csr, msg_bf, agg_bf, N);
    // updates = relu([agg | ns] @ W_upd + b_upd)  (f32 -> d_out)
    mfma_gemm_kernel<256, true, false><<<gemmGrid, 256, 0, stream>>>(
        agg_bf, ns_bf, nullptr, Wt_upd, b_upd, out, nullptr, N);
    // heads (MFMA; f32->bf16 fused in fragment load)
    head_mfma_kernel<<<gemmGrid, 256, 0, stream>>>(out, Wh, b_a1, W_a2, b_a2, b_c1, W_c2, b_c2, logits, crit, N);
    // per-graph outputs
    finalize_kernel<<<G, 1024, 0, stream>>>(logits, crit, actions, out + (size_t)N * 128, NP, G);
}